// Round 7
// baseline (449.037 us; speedup 1.0000x reference)
//
#include <hip/hip_runtime.h>
#include <hip/hip_bf16.h>

#define EPSV 1e-5f

typedef short bf16x8 __attribute__((ext_vector_type(8)));
typedef float f32x4 __attribute__((ext_vector_type(4)));

__device__ __forceinline__ float gelu_f(float x) {
    return 0.5f * x * (1.0f + erff(x * 0.70710678118654752f));
}
__device__ __forceinline__ float b2f(unsigned short u) {
    union { float f; unsigned i; } c; c.i = ((unsigned)u) << 16; return c.f;
}
__device__ __forceinline__ unsigned short f2b(float f) {
    __hip_bfloat16 h = __float2bfloat16(f);
    return *reinterpret_cast<unsigned short*>(&h);
}
__device__ __forceinline__ float lo16f(unsigned v) {
    union { float f; unsigned i; } c; c.i = v << 16; return c.f;
}
__device__ __forceinline__ float hi16f(unsigned v) {
    union { float f; unsigned i; } c; c.i = v & 0xffff0000u; return c.f;
}
// async global->LDS, 16B per lane; LDS dest = wave-uniform base + lane*16
__device__ __forceinline__ void gload16(const unsigned short* g, unsigned short* l) {
    __builtin_amdgcn_global_load_lds(
        (const __attribute__((address_space(1))) void*)g,
        (__attribute__((address_space(3))) void*)l, 16, 0, 0);
}

// ---------------------------------------------------------------- weight f32->bf16
__global__ __launch_bounds__(256) void wcvt_k(const float* __restrict__ w,
                                              unsigned short* __restrict__ o, int n4) {
    int i = blockIdx.x * 256 + threadIdx.x;
    if (i >= n4) return;
    float4 v = ((const float4*)w)[i];
    ushort4 u = make_ushort4(f2b(v.x), f2b(v.y), f2b(v.z), f2b(v.w));
    ((ushort4*)o)[i] = u;
}

// ---------------------------------------------------------------- dw weight transpose + bn2 fold
__global__ __launch_bounds__(256) void wprep_k(const float* __restrict__ wdw,
    const float* __restrict__ g, const float* __restrict__ bt,
    const float* __restrict__ mu, const float* __restrict__ va,
    float* __restrict__ wt, float* __restrict__ scf, float* __restrict__ shf) {
    int ch = blockIdx.x * 256 + threadIdx.x;   // 1024 total
    #pragma unroll
    for (int tap = 0; tap < 9; ++tap)
        wt[tap * 1024 + ch] = wdw[ch * 9 + tap];
    float s = g[ch] * rsqrtf(va[ch] + EPSV);
    scf[ch] = s;
    shf[ch] = bt[ch] - mu[ch] * s;
}

// ---------------------------------------------------------------- bn0+gelu + NCHW->NHWC
__global__ __launch_bounds__(256) void bn0tr_k(const float* __restrict__ x,
    const float* __restrict__ g, const float* __restrict__ bt,
    const float* __restrict__ mu, const float* __restrict__ va,
    unsigned short* __restrict__ h0b, float* __restrict__ xt) {
    __shared__ float tile[64][65];
    int hw0 = blockIdx.x * 64, c0 = blockIdx.y * 64, b = blockIdx.z;
    int t = threadIdx.x;
    int cl = t >> 6, hl = t & 63;
    #pragma unroll
    for (int r = 0; r < 16; ++r)
        tile[r * 4 + cl][hl] = x[((size_t)(b * 256 + c0 + r * 4 + cl)) * 1024 + hw0 + hl];
    __syncthreads();
    int c = c0 + (t & 63);
    float s = g[c] * rsqrtf(va[c] + EPSV);
    float m_ = mu[c], be = bt[c];
    #pragma unroll
    for (int r = 0; r < 16; ++r) {
        int hl2 = r * 4 + (t >> 6);
        float v = tile[t & 63][hl2];
        size_t o = ((size_t)(b * 1024 + hw0 + hl2)) * 256 + c;
        xt[o] = v;
        h0b[o] = f2b(gelu_f((v - m_) * s + be));
    }
}

// ---------------------------------------------------------------- per-window mean of gelu(bn0(x)), f32 (exact)
__global__ __launch_bounds__(256) void hm_k(const float* __restrict__ xt,
    const float* __restrict__ g, const float* __restrict__ bt,
    const float* __restrict__ mu, const float* __restrict__ va,
    float* __restrict__ hm) {
    int blk = blockIdx.x;           // b*64 + win
    int b = blk >> 6, win = blk & 63;
    int c = threadIdx.x;
    int base = (win >> 3) * 128 + (win & 7) * 4;
    float s = g[c] * rsqrtf(va[c] + EPSV);
    float m_ = mu[c], be = bt[c];
    float acc = 0.f;
    #pragma unroll
    for (int ty = 0; ty < 4; ++ty)
        #pragma unroll
        for (int tx = 0; tx < 4; ++tx) {
            float v = xt[((size_t)(b * 1024 + base + ty * 32 + tx)) * 256 + c];
            acc += gelu_f((v - m_) * s + be);
        }
    hm[(size_t)blk * 256 + c] = acc * (1.f / 16.f);
}

// ---------------------------------------------------------------- MFMA GEMM, 128x128 tile, BK=32
template <int MODE>
__global__ __launch_bounds__(256) void mgemm(
    const unsigned short* __restrict__ A, const unsigned short* __restrict__ X,
    unsigned short* __restrict__ outb, float* __restrict__ outf,
    const float* __restrict__ res,
    const float* __restrict__ p0, const float* __restrict__ p1,
    const float* __restrict__ p2, const float* __restrict__ p3,
    int M, int Kd) {
    __shared__ __align__(16) unsigned short As[4096];   // [128 m][32 k]
    __shared__ __align__(16) unsigned short Bs[4096];   // [128 n][32 k]
    const int t = threadIdx.x;
    const int wid = t >> 6, lane = t & 63;
    const int n0 = blockIdx.x * 128, m0 = blockIdx.y * 128, b = blockIdx.z;
    const unsigned short* Ab = A + (size_t)m0 * Kd;
    const unsigned short* Xb = X + ((size_t)b * 1024 + n0) * Kd;

    const int srow = lane >> 2;
    const int skb  = (lane & 3) * 8;
    const int wr = wid >> 1, wc = wid & 1;
    const int lr = lane & 15;
    const int lk = (lane >> 4) * 8;

    f32x4 acc[4][4] = {};

    for (int k0 = 0; k0 < Kd; k0 += 32) {
        #pragma unroll
        for (int i = 0; i < 2; ++i) {
            int chunk = wid * 2 + i;
            int row = chunk * 16 + srow;
            gload16(Ab + (size_t)row * Kd + k0 + skb, &As[chunk * 512]);
            gload16(Xb + (size_t)row * Kd + k0 + skb, &Bs[chunk * 512]);
        }
        __syncthreads();
        bf16x8 af[4], bfv[4];
        #pragma unroll
        for (int mi = 0; mi < 4; ++mi)
            af[mi] = *(const bf16x8*)&As[(wr * 64 + mi * 16 + lr) * 32 + lk];
        #pragma unroll
        for (int ni = 0; ni < 4; ++ni)
            bfv[ni] = *(const bf16x8*)&Bs[(wc * 64 + ni * 16 + lr) * 32 + lk];
        #pragma unroll
        for (int mi = 0; mi < 4; ++mi)
            #pragma unroll
            for (int ni = 0; ni < 4; ++ni)
                acc[mi][ni] = __builtin_amdgcn_mfma_f32_16x16x32_bf16(
                    af[mi], bfv[ni], acc[mi][ni], 0, 0, 0);
        __syncthreads();
    }

    const int crow = (lane >> 4) * 4;
    #pragma unroll
    for (int ni = 0; ni < 4; ++ni) {
        const int n = n0 + wc * 64 + ni * 16 + lr;
        #pragma unroll
        for (int mi = 0; mi < 4; ++mi) {
            const int m = m0 + wr * 64 + mi * 16 + crow;
            f32x4 v = acc[mi][ni];
            size_t o = ((size_t)b * 1024 + n) * (size_t)M + m;
            if (MODE == 0) {
                *(ushort4*)(outb + o) = make_ushort4(f2b(v[0]), f2b(v[1]), f2b(v[2]), f2b(v[3]));
            } else if (MODE == 1) {
                float4 r = *(const float4*)(res + o);
                float4 bi = *(const float4*)(p0 + m);
                float w0 = v[0] + r.x + bi.x, w1 = v[1] + r.y + bi.y;
                float w2 = v[2] + r.z + bi.z, w3 = v[3] + r.w + bi.w;
                *(float4*)(outf + o) = make_float4(w0, w1, w2, w3);
                *(ushort4*)(outb + o) = make_ushort4(f2b(w0), f2b(w1), f2b(w2), f2b(w3));
            } else if (MODE == 2) {
                float4 gg = *(const float4*)(p0 + m);
                float4 be = *(const float4*)(p1 + m);
                float4 mm = *(const float4*)(p2 + m);
                float4 vv = *(const float4*)(p3 + m);
                float h0 = gelu_f((v[0] - mm.x) * (gg.x * rsqrtf(vv.x + EPSV)) + be.x);
                float h1 = gelu_f((v[1] - mm.y) * (gg.y * rsqrtf(vv.y + EPSV)) + be.y);
                float h2 = gelu_f((v[2] - mm.z) * (gg.z * rsqrtf(vv.z + EPSV)) + be.z);
                float h3 = gelu_f((v[3] - mm.w) * (gg.w * rsqrtf(vv.w + EPSV)) + be.w);
                *(ushort4*)(outb + o) = make_ushort4(f2b(h0), f2b(h1), f2b(h2), f2b(h3));
            } else {
                float4 gg = *(const float4*)(p0 + m);
                float4 be = *(const float4*)(p1 + m);
                float4 mm = *(const float4*)(p2 + m);
                float4 vv = *(const float4*)(p3 + m);
                float4 r = *(const float4*)(res + o);
                float y0 = (v[0] - mm.x) * (gg.x * rsqrtf(vv.x + EPSV)) + be.x + r.x;
                float y1 = (v[1] - mm.y) * (gg.y * rsqrtf(vv.y + EPSV)) + be.y + r.y;
                float y2 = (v[2] - mm.z) * (gg.z * rsqrtf(vv.z + EPSV)) + be.z + r.z;
                float y3 = (v[3] - mm.w) * (gg.w * rsqrtf(vv.w + EPSV)) + be.w + r.w;
                *(float4*)(outf + o) = make_float4(y0, y1, y2, y3);
            }
        }
    }
}

// ---------------------------------------------------------------- descriptor projection (f32 exact)
// qd/kd[b*64+win][t] = dot(w_qkv[row t (q) / 256+t (k)], hm[b*64+win])
__global__ __launch_bounds__(256) void desc_k(const float* __restrict__ hm,
                                              const float* __restrict__ w_qkv,
                                              float* __restrict__ qd,
                                              float* __restrict__ kd) {
    int blk = blockIdx.x;           // b*64 + win (1024)
    __shared__ float hrow[256];
    int t = threadIdx.x;
    hrow[t] = hm[(size_t)blk * 256 + t];
    __syncthreads();
    const float4* wq = (const float4*)(w_qkv + (size_t)t * 256);
    const float4* wk = (const float4*)(w_qkv + (size_t)(256 + t) * 256);
    float sq = 0.f, sk = 0.f;
    #pragma unroll 8
    for (int c4 = 0; c4 < 64; ++c4) {
        float4 a = wq[c4];
        float4 b = wk[c4];
        float h0 = hrow[c4 * 4], h1 = hrow[c4 * 4 + 1];
        float h2 = hrow[c4 * 4 + 2], h3 = hrow[c4 * 4 + 3];
        sq += a.x * h0 + a.y * h1 + a.z * h2 + a.w * h3;
        sk += b.x * h0 + b.y * h1 + b.z * h2 + b.w * h3;
    }
    qd[(size_t)blk * 256 + t] = sq;
    kd[(size_t)blk * 256 + t] = sk;
}

// ---------------------------------------------------------------- affinity + top-4 per (b,h)
__global__ __launch_bounds__(256) void aff_k(const float* __restrict__ qd,
                                             const float* __restrict__ kd,
                                             int* __restrict__ idx_out) {
    int bh = blockIdx.x;            // b*8 + h (128)
    int b = bh >> 3, h = bh & 7;
    __shared__ float qdl[64][33];
    __shared__ float kdl[64][33];
    __shared__ float wsc[64][65];
    int t = threadIdx.x;
    for (int e = t; e < 2048; e += 256) {
        int wn = e >> 5, d = e & 31;
        size_t src = ((size_t)(b * 64 + wn)) * 256 + h * 32 + d;
        qdl[wn][d] = qd[src];
        kdl[wn][d] = kd[src];
    }
    __syncthreads();
    {
        int i = t >> 2, j0 = (t & 3) * 16;
        float s[16];
        #pragma unroll
        for (int j = 0; j < 16; ++j) s[j] = 0.f;
        #pragma unroll
        for (int d = 0; d < 32; ++d) {
            float qv = qdl[i][d];
            #pragma unroll
            for (int j = 0; j < 16; ++j) s[j] += qv * kdl[j0 + j][d];
        }
        #pragma unroll
        for (int j = 0; j < 16; ++j) wsc[i][j0 + j] = s[j];
    }
    __syncthreads();
    if (t < 64) {
        float bv[4] = {-1e30f, -1e30f, -1e30f, -1e30f};
        int   bi[4] = {0, 0, 0, 0};
        for (int j = 0; j < 64; ++j) {
            float v = wsc[t][j];
            if (v > bv[3]) {
                int p = 3;
                while (p > 0 && v > bv[p - 1]) {
                    bv[p] = bv[p - 1]; bi[p] = bi[p - 1]; --p;
                }
                bv[p] = v; bi[p] = j;
            }
        }
        int* o = idx_out + (bh * 64 + t) * 4;
        o[0] = bi[0]; o[1] = bi[1]; o[2] = bi[2]; o[3] = bi[3];
    }
}

// ---------------------------------------------------------------- gathered window attention (NHWC bf16)
__global__ __launch_bounds__(256) void attn_k(const unsigned short* __restrict__ qkv,
                                              const int* __restrict__ idx,
                                              unsigned short* __restrict__ msg) {
    int blk = blockIdx.x;
    int win = blk & 63;
    int bh = blk >> 6;
    int b = bh >> 3, h = bh & 7;
    __shared__ float qs[16][32];
    __shared__ float ks[64][32];
    __shared__ float vs[64][32];
    __shared__ float sc[16][64];
    __shared__ int widx[4];
    int t = threadIdx.x;
    if (t < 4) widx[t] = idx[(bh * 64 + win) * 4 + t];
    __syncthreads();
    int qb = (win >> 3) * 128 + (win & 7) * 4;
    for (int e = t; e < 512; e += 256) {
        int tok = e >> 5, d = e & 31;
        int hw = qb + (tok >> 2) * 32 + (tok & 3);
        qs[tok][d] = b2f(qkv[((size_t)(b * 1024 + hw)) * 768 + h * 32 + d]);
    }
    for (int e = t; e < 2048; e += 256) {
        int key = e >> 5, d = e & 31;
        int wsel = widx[key >> 4];
        int tok = key & 15;
        int hw = (wsel >> 3) * 128 + (wsel & 7) * 4 + (tok >> 2) * 32 + (tok & 3);
        size_t base = ((size_t)(b * 1024 + hw)) * 768 + h * 32 + d;
        ks[key][d] = b2f(qkv[base + 256]);
        vs[key][d] = b2f(qkv[base + 512]);
    }
    __syncthreads();
    const float scale = 0.17677669529663688f;
    for (int e = t; e < 1024; e += 256) {
        int r = e >> 6, cidx = e & 63;
        float s = 0.f;
        #pragma unroll
        for (int d = 0; d < 32; ++d) s += qs[r][d] * ks[cidx][d];
        sc[r][cidx] = s * scale;
    }
    __syncthreads();
    {
        int r = t >> 4, c0 = (t & 15) << 2;
        float v0 = sc[r][c0], v1 = sc[r][c0 + 1], v2 = sc[r][c0 + 2], v3 = sc[r][c0 + 3];
        float mx = fmaxf(fmaxf(v0, v1), fmaxf(v2, v3));
        #pragma unroll
        for (int m = 1; m < 16; m <<= 1) mx = fmaxf(mx, __shfl_xor(mx, m));
        float e0 = expf(v0 - mx), e1 = expf(v1 - mx), e2 = expf(v2 - mx), e3 = expf(v3 - mx);
        float sm = e0 + e1 + e2 + e3;
        #pragma unroll
        for (int m = 1; m < 16; m <<= 1) sm += __shfl_xor(sm, m);
        float inv = 1.0f / sm;
        sc[r][c0] = e0 * inv; sc[r][c0 + 1] = e1 * inv;
        sc[r][c0 + 2] = e2 * inv; sc[r][c0 + 3] = e3 * inv;
    }
    __syncthreads();
    for (int e = t; e < 512; e += 256) {
        int tok = e >> 5, d = e & 31;
        float s = 0.f;
        #pragma unroll
        for (int kk = 0; kk < 64; ++kk) s += sc[tok][kk] * vs[kk][d];
        int hw = qb + (tok >> 2) * 32 + (tok & 3);
        msg[((size_t)(b * 1024 + hw)) * 256 + h * 32 + d] = f2b(s);
    }
}

// ---------------------------------------------------------------- K5: depthwise 3x3 + bn2 + gelu, vectorized
__global__ __launch_bounds__(256) void dw_k(const unsigned short* __restrict__ h1,
    const float* __restrict__ wt, const float* __restrict__ scf,
    const float* __restrict__ shf, unsigned short* __restrict__ h2) {
    int t = threadIdx.x;
    int c8 = t & 127;             // channel octet 0..127
    int pl = t >> 7;              // 0/1
    int blk = blockIdx.x;         // 2048 total: b(16) * y(32) * xg(4)
    int b = blk >> 7;
    int rem = blk & 127;
    int y = rem >> 2;
    int x0 = (rem & 3) * 8;
    int ch0 = c8 * 8;

    float w[9][8];
    #pragma unroll
    for (int tap = 0; tap < 9; ++tap) {
        float4 a = *(const float4*)(wt + tap * 1024 + ch0);
        float4 bq = *(const float4*)(wt + tap * 1024 + ch0 + 4);
        w[tap][0] = a.x; w[tap][1] = a.y; w[tap][2] = a.z; w[tap][3] = a.w;
        w[tap][4] = bq.x; w[tap][5] = bq.y; w[tap][6] = bq.z; w[tap][7] = bq.w;
    }
    float sc[8], sh[8];
    {
        float4 a = *(const float4*)(scf + ch0);
        float4 bq = *(const float4*)(scf + ch0 + 4);
        sc[0]=a.x; sc[1]=a.y; sc[2]=a.z; sc[3]=a.w; sc[4]=bq.x; sc[5]=bq.y; sc[6]=bq.z; sc[7]=bq.w;
        float4 c = *(const float4*)(shf + ch0);
        float4 dq = *(const float4*)(shf + ch0 + 4);
        sh[0]=c.x; sh[1]=c.y; sh[2]=c.z; sh[3]=c.w; sh[4]=dq.x; sh[5]=dq.y; sh[6]=dq.z; sh[7]=dq.w;
    }

    const unsigned short* base = h1 + (size_t)b * 1048576;
    unsigned short* ob = h2 + (size_t)b * 1048576;

    #pragma unroll
    for (int j = 0; j < 4; ++j) {
        int x = x0 + pl + 2 * j;
        float acc[8] = {0.f,0.f,0.f,0.f,0.f,0.f,0.f,0.f};
        #pragma unroll
        for (int dy = -1; dy <= 1; ++dy) {
            int yy = y + dy;
            if (yy < 0 || yy > 31) continue;
            #pragma unroll
            for (int dx = -1; dx <= 1; ++dx) {
                int xx = x + dx;
                if (xx < 0 || xx > 31) continue;
                uint4 u = *(const uint4*)(base + (size_t)(yy * 32 + xx) * 1024 + ch0);
                int tap = (dy + 1) * 3 + (dx + 1);
                acc[0] += lo16f(u.x) * w[tap][0];
                acc[1] += hi16f(u.x) * w[tap][1];
                acc[2] += lo16f(u.y) * w[tap][2];
                acc[3] += hi16f(u.y) * w[tap][3];
                acc[4] += lo16f(u.z) * w[tap][4];
                acc[5] += hi16f(u.z) * w[tap][5];
                acc[6] += lo16f(u.w) * w[tap][6];
                acc[7] += hi16f(u.w) * w[tap][7];
            }
        }
        unsigned short r[8];
        #pragma unroll
        for (int c = 0; c < 8; ++c)
            r[c] = f2b(gelu_f(acc[c] * sc[c] + sh[c]));
        uint4 o;
        o.x = (unsigned)r[0] | ((unsigned)r[1] << 16);
        o.y = (unsigned)r[2] | ((unsigned)r[3] << 16);
        o.z = (unsigned)r[4] | ((unsigned)r[5] << 16);
        o.w = (unsigned)r[6] | ((unsigned)r[7] << 16);
        *(uint4*)(ob + (size_t)(y * 32 + x) * 1024 + ch0) = o;
    }
}

// ---------------------------------------------------------------- NHWC f32 -> NCHW f32 (final)
__global__ __launch_bounds__(256) void trout_k(const float* __restrict__ y,
                                               float* __restrict__ out) {
    __shared__ float tile[64][65];
    int hw0 = blockIdx.x * 64, c0 = blockIdx.y * 64, b = blockIdx.z;
    int t = threadIdx.x;
    #pragma unroll
    for (int r = 0; r < 16; ++r) {
        int hl = r * 4 + (t >> 6);
        tile[t & 63][hl] = y[((size_t)(b * 1024 + hw0 + hl)) * 256 + c0 + (t & 63)];
    }
    __syncthreads();
    #pragma unroll
    for (int r = 0; r < 16; ++r) {
        int cl = r * 4 + (t >> 6);
        out[((size_t)(b * 256 + c0 + cl)) * 1024 + hw0 + (t & 63)] = tile[cl][t & 63];
    }
}

// ---------------------------------------------------------------- launch
extern "C" void kernel_launch(void* const* d_in, const int* in_sizes, int n_in,
                              void* d_out, int out_size, void* d_ws, size_t ws_size,
                              hipStream_t stream) {
    const float* x      = (const float*)d_in[0];
    const float* bn0_g  = (const float*)d_in[1];
    const float* bn0_b  = (const float*)d_in[2];
    const float* bn0_m  = (const float*)d_in[3];
    const float* bn0_v  = (const float*)d_in[4];
    const float* w_qkv  = (const float*)d_in[5];
    const float* w_merge= (const float*)d_in[6];
    const float* b_merge= (const float*)d_in[7];
    const float* w1     = (const float*)d_in[8];
    const float* bn1_g  = (const float*)d_in[9];
    const float* bn1_b  = (const float*)d_in[10];
    const float* bn1_m  = (const float*)d_in[11];
    const float* bn1_v  = (const float*)d_in[12];
    const float* dw     = (const float*)d_in[13];
    const float* bn2_g  = (const float*)d_in[14];
    const float* bn2_b  = (const float*)d_in[15];
    const float* bn2_m  = (const float*)d_in[16];
    const float* bn2_v  = (const float*)d_in[17];
    const float* w2     = (const float*)d_in[18];
    const float* bn3_g  = (const float*)d_in[19];
    const float* bn3_b  = (const float*)d_in[20];
    const float* bn3_m  = (const float*)d_in[21];
    const float* bn3_v  = (const float*)d_in[22];
    float* out = (float*)d_out;

    char* w = (char*)d_ws;
    unsigned short* h0b   = (unsigned short*)(w);                // [b][hw][256] bf16
    unsigned short* qkvb  = (unsigned short*)(w + 8388608);      // [b][hw][768] bf16
    unsigned short* msgb  = (unsigned short*)(w + 33554432);     // [b][hw][256] bf16
    unsigned short* xrb   = (unsigned short*)(w + 41943040);     // [b][hw][256] bf16
    unsigned short* h1b   = (unsigned short*)(w + 50331648);     // [b][hw][1024] bf16
    unsigned short* h2b   = (unsigned short*)(w + 83886080);     // [b][hw][1024] bf16
    float*  xt    = (float*)(w + 117440512);                     // [b][hw][256] f32 (raw x)
    float*  xrf   = (float*)(w + 134217728);                     // [b][hw][256] f32
    float*  yf    = (float*)(w + 150994944);                     // [b][hw][256] f32
    float*  hm    = (float*)(w + 167772160);                     // [b][64][256] f32
    unsigned short* wqkvb = (unsigned short*)(w + 168820736);
    unsigned short* wmrgb = (unsigned short*)(w + 169213952);
    unsigned short* w1b   = (unsigned short*)(w + 169345024);
    unsigned short* w2b   = (unsigned short*)(w + 169869312);
    int*    idx   = (int*)(w + 170393600);                       // 131072 B
    float*  wtbuf = (float*)(w + 170524672);                     // 9*1024 f32
    float*  scbuf = (float*)(w + 170561536);                     // 1024 f32
    float*  shbuf = (float*)(w + 170565632);                     // 1024 f32
    float*  qdbuf = (float*)(w + 170569728);                     // [b*64][256] f32 (1 MB)
    float*  kdbuf = (float*)(w + 171618304);                     // [b*64][256] f32 (1 MB)

    // weights -> bf16 + dw prep
    wcvt_k<<<192, 256, 0, stream>>>(w_qkv, wqkvb, 49152);
    wcvt_k<<<64,  256, 0, stream>>>(w_merge, wmrgb, 16384);
    wcvt_k<<<256, 256, 0, stream>>>(w1, w1b, 65536);
    wcvt_k<<<256, 256, 0, stream>>>(w2, w2b, 65536);
    wprep_k<<<4, 256, 0, stream>>>(dw, bn2_g, bn2_b, bn2_m, bn2_v, wtbuf, scbuf, shbuf);

    // bn0+gelu + transpose to NHWC
    bn0tr_k<<<dim3(16, 4, 16), 256, 0, stream>>>(x, bn0_g, bn0_b, bn0_m, bn0_v, h0b, xt);
    // exact f32 window means
    hm_k<<<1024, 256, 0, stream>>>(xt, bn0_g, bn0_b, bn0_m, bn0_v, hm);
    // qkv = w_qkv @ h0
    mgemm<0><<<dim3(8, 6, 16), 256, 0, stream>>>(wqkvb, h0b, qkvb, nullptr,
        nullptr, nullptr, nullptr, nullptr, nullptr, 768, 256);
    // descriptors + top-k (f32-exact, well-parallelized)
    desc_k<<<1024, 256, 0, stream>>>(hm, w_qkv, qdbuf, kdbuf);
    aff_k<<<128, 256, 0, stream>>>(qdbuf, kdbuf, idx);
    // attention
    attn_k<<<8192, 256, 0, stream>>>(qkvb, idx, msgb);
    // xr = x + w_merge@msg + bias
    mgemm<1><<<dim3(8, 2, 16), 256, 0, stream>>>(wmrgb, msgb, xrb, xrf,
        xt, b_merge, nullptr, nullptr, nullptr, 256, 256);
    // h1 = gelu(bn1(w1@xr))
    mgemm<2><<<dim3(8, 8, 16), 256, 0, stream>>>(w1b, xrb, h1b, nullptr,
        nullptr, bn1_g, bn1_b, bn1_m, bn1_v, 1024, 256);
    // h2 = gelu(bn2(dw3x3(h1)))  — vectorized
    dw_k<<<2048, 256, 0, stream>>>(h1b, wtbuf, scbuf, shbuf, h2b);
    // y = bn3(w2@h2) + xr  (f32 NHWC)
    mgemm<3><<<dim3(8, 2, 16), 256, 0, stream>>>(w2b, h2b, nullptr, yf,
        xrf, bn3_g, bn3_b, bn3_m, bn3_v, 256, 1024);
    // NHWC -> NCHW
    trout_k<<<dim3(16, 4, 16), 256, 0, stream>>>(yf, out);
}

// Round 9
// 377.651 us; speedup vs baseline: 1.1890x; 1.1890x over previous
//
#include <hip/hip_runtime.h>
#include <hip/hip_bf16.h>

#define EPSV 1e-5f

typedef short bf16x8 __attribute__((ext_vector_type(8)));
typedef float f32x4 __attribute__((ext_vector_type(4)));

__device__ __forceinline__ float gelu_f(float x) {
    return 0.5f * x * (1.0f + erff(x * 0.70710678118654752f));
}
__device__ __forceinline__ float b2f(unsigned short u) {
    union { float f; unsigned i; } c; c.i = ((unsigned)u) << 16; return c.f;
}
__device__ __forceinline__ unsigned short f2b(float f) {
    __hip_bfloat16 h = __float2bfloat16(f);
    return *reinterpret_cast<unsigned short*>(&h);
}
__device__ __forceinline__ float lo16f(unsigned v) {
    union { float f; unsigned i; } c; c.i = v << 16; return c.f;
}
__device__ __forceinline__ float hi16f(unsigned v) {
    union { float f; unsigned i; } c; c.i = v & 0xffff0000u; return c.f;
}
// async global->LDS, 16B per lane; LDS dest = wave-uniform base + lane*16
__device__ __forceinline__ void gload16(const unsigned short* g, unsigned short* l) {
    __builtin_amdgcn_global_load_lds(
        (const __attribute__((address_space(1))) void*)g,
        (__attribute__((address_space(3))) void*)l, 16, 0, 0);
}

// ---------------------------------------------------------------- weight f32->bf16
__global__ __launch_bounds__(256) void wcvt_k(const float* __restrict__ w,
                                              unsigned short* __restrict__ o, int n4) {
    int i = blockIdx.x * 256 + threadIdx.x;
    if (i >= n4) return;
    float4 v = ((const float4*)w)[i];
    ushort4 u = make_ushort4(f2b(v.x), f2b(v.y), f2b(v.z), f2b(v.w));
    ((ushort4*)o)[i] = u;
}

// ---------------------------------------------------------------- dw weight transpose + bn2 fold
__global__ __launch_bounds__(256) void wprep_k(const float* __restrict__ wdw,
    const float* __restrict__ g, const float* __restrict__ bt,
    const float* __restrict__ mu, const float* __restrict__ va,
    float* __restrict__ wt, float* __restrict__ scf, float* __restrict__ shf) {
    int ch = blockIdx.x * 256 + threadIdx.x;   // 1024 total
    #pragma unroll
    for (int tap = 0; tap < 9; ++tap)
        wt[tap * 1024 + ch] = wdw[ch * 9 + tap];
    float s = g[ch] * rsqrtf(va[ch] + EPSV);
    scf[ch] = s;
    shf[ch] = bt[ch] - mu[ch] * s;
}

// ---------------------------------------------------------------- bn0+gelu + NCHW->NHWC
__global__ __launch_bounds__(256) void bn0tr_k(const float* __restrict__ x,
    const float* __restrict__ g, const float* __restrict__ bt,
    const float* __restrict__ mu, const float* __restrict__ va,
    unsigned short* __restrict__ h0b, float* __restrict__ xt) {
    __shared__ float tile[64][65];
    int hw0 = blockIdx.x * 64, c0 = blockIdx.y * 64, b = blockIdx.z;
    int t = threadIdx.x;
    int cl = t >> 6, hl = t & 63;
    #pragma unroll
    for (int r = 0; r < 16; ++r)
        tile[r * 4 + cl][hl] = x[((size_t)(b * 256 + c0 + r * 4 + cl)) * 1024 + hw0 + hl];
    __syncthreads();
    int c = c0 + (t & 63);
    float s = g[c] * rsqrtf(va[c] + EPSV);
    float m_ = mu[c], be = bt[c];
    #pragma unroll
    for (int r = 0; r < 16; ++r) {
        int hl2 = r * 4 + (t >> 6);
        float v = tile[t & 63][hl2];
        size_t o = ((size_t)(b * 1024 + hw0 + hl2)) * 256 + c;
        xt[o] = v;
        h0b[o] = f2b(gelu_f((v - m_) * s + be));
    }
}

// ---------------------------------------------------------------- per-window mean of gelu(bn0(x)), f32 (exact)
__global__ __launch_bounds__(256) void hm_k(const float* __restrict__ xt,
    const float* __restrict__ g, const float* __restrict__ bt,
    const float* __restrict__ mu, const float* __restrict__ va,
    float* __restrict__ hm) {
    int blk = blockIdx.x;           // b*64 + win
    int b = blk >> 6, win = blk & 63;
    int c = threadIdx.x;
    int base = (win >> 3) * 128 + (win & 7) * 4;
    float s = g[c] * rsqrtf(va[c] + EPSV);
    float m_ = mu[c], be = bt[c];
    float acc = 0.f;
    #pragma unroll
    for (int ty = 0; ty < 4; ++ty)
        #pragma unroll
        for (int tx = 0; tx < 4; ++tx) {
            float v = xt[((size_t)(b * 1024 + base + ty * 32 + tx)) * 256 + c];
            acc += gelu_f((v - m_) * s + be);
        }
    hm[(size_t)blk * 256 + c] = acc * (1.f / 16.f);
}

// ---------------------------------------------------------------- MFMA GEMM, 128x128 tile, BK=32
template <int MODE>
__global__ __launch_bounds__(256) void mgemm(
    const unsigned short* __restrict__ A, const unsigned short* __restrict__ X,
    unsigned short* __restrict__ outb, float* __restrict__ outf,
    const float* __restrict__ res,
    const float* __restrict__ p0, const float* __restrict__ p1,
    const float* __restrict__ p2, const float* __restrict__ p3,
    int M, int Kd) {
    __shared__ __align__(16) unsigned short As[4096];   // [128 m][32 k]
    __shared__ __align__(16) unsigned short Bs[4096];   // [128 n][32 k]
    const int t = threadIdx.x;
    const int wid = t >> 6, lane = t & 63;
    const int n0 = blockIdx.x * 128, m0 = blockIdx.y * 128, b = blockIdx.z;
    const unsigned short* Ab = A + (size_t)m0 * Kd;
    const unsigned short* Xb = X + ((size_t)b * 1024 + n0) * Kd;

    const int srow = lane >> 2;
    const int skb  = (lane & 3) * 8;
    const int wr = wid >> 1, wc = wid & 1;
    const int lr = lane & 15;
    const int lk = (lane >> 4) * 8;

    f32x4 acc[4][4] = {};

    for (int k0 = 0; k0 < Kd; k0 += 32) {
        #pragma unroll
        for (int i = 0; i < 2; ++i) {
            int chunk = wid * 2 + i;
            int row = chunk * 16 + srow;
            gload16(Ab + (size_t)row * Kd + k0 + skb, &As[chunk * 512]);
            gload16(Xb + (size_t)row * Kd + k0 + skb, &Bs[chunk * 512]);
        }
        __syncthreads();
        bf16x8 af[4], bfv[4];
        #pragma unroll
        for (int mi = 0; mi < 4; ++mi)
            af[mi] = *(const bf16x8*)&As[(wr * 64 + mi * 16 + lr) * 32 + lk];
        #pragma unroll
        for (int ni = 0; ni < 4; ++ni)
            bfv[ni] = *(const bf16x8*)&Bs[(wc * 64 + ni * 16 + lr) * 32 + lk];
        #pragma unroll
        for (int mi = 0; mi < 4; ++mi)
            #pragma unroll
            for (int ni = 0; ni < 4; ++ni)
                acc[mi][ni] = __builtin_amdgcn_mfma_f32_16x16x32_bf16(
                    af[mi], bfv[ni], acc[mi][ni], 0, 0, 0);
        __syncthreads();
    }

    const int crow = (lane >> 4) * 4;
    #pragma unroll
    for (int ni = 0; ni < 4; ++ni) {
        const int n = n0 + wc * 64 + ni * 16 + lr;
        #pragma unroll
        for (int mi = 0; mi < 4; ++mi) {
            const int m = m0 + wr * 64 + mi * 16 + crow;
            f32x4 v = acc[mi][ni];
            size_t o = ((size_t)b * 1024 + n) * (size_t)M + m;
            if (MODE == 0) {
                *(ushort4*)(outb + o) = make_ushort4(f2b(v[0]), f2b(v[1]), f2b(v[2]), f2b(v[3]));
            } else if (MODE == 1) {
                float4 r = *(const float4*)(res + o);
                float4 bi = *(const float4*)(p0 + m);
                float w0 = v[0] + r.x + bi.x, w1 = v[1] + r.y + bi.y;
                float w2 = v[2] + r.z + bi.z, w3 = v[3] + r.w + bi.w;
                *(float4*)(outf + o) = make_float4(w0, w1, w2, w3);
                *(ushort4*)(outb + o) = make_ushort4(f2b(w0), f2b(w1), f2b(w2), f2b(w3));
            } else if (MODE == 2) {
                float4 gg = *(const float4*)(p0 + m);
                float4 be = *(const float4*)(p1 + m);
                float4 mm = *(const float4*)(p2 + m);
                float4 vv = *(const float4*)(p3 + m);
                float h0 = gelu_f((v[0] - mm.x) * (gg.x * rsqrtf(vv.x + EPSV)) + be.x);
                float h1 = gelu_f((v[1] - mm.y) * (gg.y * rsqrtf(vv.y + EPSV)) + be.y);
                float h2 = gelu_f((v[2] - mm.z) * (gg.z * rsqrtf(vv.z + EPSV)) + be.z);
                float h3 = gelu_f((v[3] - mm.w) * (gg.w * rsqrtf(vv.w + EPSV)) + be.w);
                *(ushort4*)(outb + o) = make_ushort4(f2b(h0), f2b(h1), f2b(h2), f2b(h3));
            } else {
                float4 gg = *(const float4*)(p0 + m);
                float4 be = *(const float4*)(p1 + m);
                float4 mm = *(const float4*)(p2 + m);
                float4 vv = *(const float4*)(p3 + m);
                float4 r = *(const float4*)(res + o);
                float y0 = (v[0] - mm.x) * (gg.x * rsqrtf(vv.x + EPSV)) + be.x + r.x;
                float y1 = (v[1] - mm.y) * (gg.y * rsqrtf(vv.y + EPSV)) + be.y + r.y;
                float y2 = (v[2] - mm.z) * (gg.z * rsqrtf(vv.z + EPSV)) + be.z + r.z;
                float y3 = (v[3] - mm.w) * (gg.w * rsqrtf(vv.w + EPSV)) + be.w + r.w;
                *(float4*)(outf + o) = make_float4(y0, y1, y2, y3);
            }
        }
    }
}

// ---------------------------------------------------------------- descriptor GEMM (f32 exact, tiled)
// qkd[row][o] = sum_c hm[row][c] * w_qkv[o][c]; row<1024 (b*64+win), o<512 (q:0-255, k:256-511)
__global__ __launch_bounds__(256) void desc2_k(const float* __restrict__ hm,
                                               const float* __restrict__ w_qkv,
                                               float* __restrict__ qkd) {
    __shared__ float As[16][64];   // [k][o]   weights (LDS-transposed)
    __shared__ float Bs[16][64];   // [k][row] hm      (LDS-transposed)
    float acc[4][4] = {{0.f}};
    const int t = threadIdx.x;
    const int tn = t & 15, tm = t >> 4;
    const int n0 = blockIdx.x * 64;   // row tile
    const int m0 = blockIdx.y * 64;   // output tile
    for (int k0 = 0; k0 < 256; k0 += 16) {
        {
            int r  = t >> 2;
            int k4 = (t & 3) << 2;
            float4 a4 = *(const float4*)(w_qkv + (size_t)(m0 + r) * 256 + k0 + k4);
            As[k4 + 0][r] = a4.x; As[k4 + 1][r] = a4.y;
            As[k4 + 2][r] = a4.z; As[k4 + 3][r] = a4.w;
            float4 b4 = *(const float4*)(hm + (size_t)(n0 + r) * 256 + k0 + k4);
            Bs[k4 + 0][r] = b4.x; Bs[k4 + 1][r] = b4.y;
            Bs[k4 + 2][r] = b4.z; Bs[k4 + 3][r] = b4.w;
        }
        __syncthreads();
        #pragma unroll
        for (int kk = 0; kk < 16; ++kk) {
            float4 av = *(const float4*)&As[kk][tm << 2];
            float4 bv = *(const float4*)&Bs[kk][tn << 2];
            float a0[4] = {av.x, av.y, av.z, av.w};
            float b0[4] = {bv.x, bv.y, bv.z, bv.w};
            #pragma unroll
            for (int i = 0; i < 4; ++i)
                #pragma unroll
                for (int j = 0; j < 4; ++j)
                    acc[i][j] += a0[i] * b0[j];
        }
        __syncthreads();
    }
    #pragma unroll
    for (int j = 0; j < 4; ++j) {
        int row = n0 + (tn << 2) + j;
        float4 v = make_float4(acc[0][j], acc[1][j], acc[2][j], acc[3][j]);
        *(float4*)(qkd + (size_t)row * 512 + m0 + (tm << 2)) = v;
    }
}

// ---------------------------------------------------------------- affinity + top-4 per (b,h)
__global__ __launch_bounds__(256) void aff_k(const float* __restrict__ qkd,
                                             int* __restrict__ idx_out) {
    int bh = blockIdx.x;            // b*8 + h (128)
    int b = bh >> 3, h = bh & 7;
    __shared__ float qdl[64][33];
    __shared__ float kdl[64][33];
    __shared__ float wsc[64][65];
    int t = threadIdx.x;
    for (int e = t; e < 2048; e += 256) {
        int wn = e >> 5, d = e & 31;
        size_t src = ((size_t)(b * 64 + wn)) * 512 + h * 32 + d;
        qdl[wn][d] = qkd[src];
        kdl[wn][d] = qkd[src + 256];
    }
    __syncthreads();
    {
        int i = t >> 2, j0 = (t & 3) * 16;
        float s[16];
        #pragma unroll
        for (int j = 0; j < 16; ++j) s[j] = 0.f;
        #pragma unroll
        for (int d = 0; d < 32; ++d) {
            float qv = qdl[i][d];
            #pragma unroll
            for (int j = 0; j < 16; ++j) s[j] += qv * kdl[j0 + j][d];
        }
        #pragma unroll
        for (int j = 0; j < 16; ++j) wsc[i][j0 + j] = s[j];
    }
    __syncthreads();
    if (t < 64) {
        float bv[4] = {-1e30f, -1e30f, -1e30f, -1e30f};
        int   bi[4] = {0, 0, 0, 0};
        for (int j = 0; j < 64; ++j) {
            float v = wsc[t][j];
            if (v > bv[3]) {
                int p = 3;
                while (p > 0 && v > bv[p - 1]) {
                    bv[p] = bv[p - 1]; bi[p] = bi[p - 1]; --p;
                }
                bv[p] = v; bi[p] = j;
            }
        }
        int* o = idx_out + (bh * 64 + t) * 4;
        o[0] = bi[0]; o[1] = bi[1]; o[2] = bi[2]; o[3] = bi[3];
    }
}

// ---------------------------------------------------------------- gathered window attention (NHWC bf16)
__global__ __launch_bounds__(256) void attn_k(const unsigned short* __restrict__ qkv,
                                              const int* __restrict__ idx,
                                              unsigned short* __restrict__ msg) {
    int blk = blockIdx.x;
    int win = blk & 63;
    int bh = blk >> 6;
    int b = bh >> 3, h = bh & 7;
    __shared__ float qs[16][32];
    __shared__ float ks[64][32];
    __shared__ float vs[64][32];
    __shared__ float sc[16][64];
    __shared__ int widx[4];
    int t = threadIdx.x;
    if (t < 4) widx[t] = idx[(bh * 64 + win) * 4 + t];
    __syncthreads();
    int qb = (win >> 3) * 128 + (win & 7) * 4;
    for (int e = t; e < 512; e += 256) {
        int tok = e >> 5, d = e & 31;
        int hw = qb + (tok >> 2) * 32 + (tok & 3);
        qs[tok][d] = b2f(qkv[((size_t)(b * 1024 + hw)) * 768 + h * 32 + d]);
    }
    for (int e = t; e < 2048; e += 256) {
        int key = e >> 5, d = e & 31;
        int wsel = widx[key >> 4];
        int tok = key & 15;
        int hw = (wsel >> 3) * 128 + (wsel & 7) * 4 + (tok >> 2) * 32 + (tok & 3);
        size_t base = ((size_t)(b * 1024 + hw)) * 768 + h * 32 + d;
        ks[key][d] = b2f(qkv[base + 256]);
        vs[key][d] = b2f(qkv[base + 512]);
    }
    __syncthreads();
    const float scale = 0.17677669529663688f;
    for (int e = t; e < 1024; e += 256) {
        int r = e >> 6, cidx = e & 63;
        float s = 0.f;
        #pragma unroll
        for (int d = 0; d < 32; ++d) s += qs[r][d] * ks[cidx][d];
        sc[r][cidx] = s * scale;
    }
    __syncthreads();
    {
        int r = t >> 4, c0 = (t & 15) << 2;
        float v0 = sc[r][c0], v1 = sc[r][c0 + 1], v2 = sc[r][c0 + 2], v3 = sc[r][c0 + 3];
        float mx = fmaxf(fmaxf(v0, v1), fmaxf(v2, v3));
        #pragma unroll
        for (int m = 1; m < 16; m <<= 1) mx = fmaxf(mx, __shfl_xor(mx, m));
        float e0 = expf(v0 - mx), e1 = expf(v1 - mx), e2 = expf(v2 - mx), e3 = expf(v3 - mx);
        float sm = e0 + e1 + e2 + e3;
        #pragma unroll
        for (int m = 1; m < 16; m <<= 1) sm += __shfl_xor(sm, m);
        float inv = 1.0f / sm;
        sc[r][c0] = e0 * inv; sc[r][c0 + 1] = e1 * inv;
        sc[r][c0 + 2] = e2 * inv; sc[r][c0 + 3] = e3 * inv;
    }
    __syncthreads();
    for (int e = t; e < 512; e += 256) {
        int tok = e >> 5, d = e & 31;
        float s = 0.f;
        #pragma unroll
        for (int kk = 0; kk < 64; ++kk) s += sc[tok][kk] * vs[kk][d];
        int hw = qb + (tok >> 2) * 32 + (tok & 3);
        msg[((size_t)(b * 1024 + hw)) * 256 + h * 32 + d] = f2b(s);
    }
}

// ---------------------------------------------------------------- K5: depthwise 3x3 + bn2 + gelu, vectorized
__global__ __launch_bounds__(256) void dw_k(const unsigned short* __restrict__ h1,
    const float* __restrict__ wt, const float* __restrict__ scf,
    const float* __restrict__ shf, unsigned short* __restrict__ h2) {
    int t = threadIdx.x;
    int c8 = t & 127;             // channel octet 0..127
    int pl = t >> 7;              // 0/1
    int blk = blockIdx.x;         // 2048 total: b(16) * y(32) * xg(4)
    int b = blk >> 7;
    int rem = blk & 127;
    int y = rem >> 2;
    int x0 = (rem & 3) * 8;
    int ch0 = c8 * 8;

    float w[9][8];
    #pragma unroll
    for (int tap = 0; tap < 9; ++tap) {
        float4 a = *(const float4*)(wt + tap * 1024 + ch0);
        float4 bq = *(const float4*)(wt + tap * 1024 + ch0 + 4);
        w[tap][0] = a.x; w[tap][1] = a.y; w[tap][2] = a.z; w[tap][3] = a.w;
        w[tap][4] = bq.x; w[tap][5] = bq.y; w[tap][6] = bq.z; w[tap][7] = bq.w;
    }
    float sc[8], sh[8];
    {
        float4 a = *(const float4*)(scf + ch0);
        float4 bq = *(const float4*)(scf + ch0 + 4);
        sc[0]=a.x; sc[1]=a.y; sc[2]=a.z; sc[3]=a.w; sc[4]=bq.x; sc[5]=bq.y; sc[6]=bq.z; sc[7]=bq.w;
        float4 c = *(const float4*)(shf + ch0);
        float4 dq = *(const float4*)(shf + ch0 + 4);
        sh[0]=c.x; sh[1]=c.y; sh[2]=c.z; sh[3]=c.w; sh[4]=dq.x; sh[5]=dq.y; sh[6]=dq.z; sh[7]=dq.w;
    }

    const unsigned short* base = h1 + (size_t)b * 1048576;
    unsigned short* ob = h2 + (size_t)b * 1048576;

    #pragma unroll
    for (int j = 0; j < 4; ++j) {
        int x = x0 + pl + 2 * j;
        float acc[8] = {0.f,0.f,0.f,0.f,0.f,0.f,0.f,0.f};
        #pragma unroll
        for (int dy = -1; dy <= 1; ++dy) {
            int yy = y + dy;
            if (yy < 0 || yy > 31) continue;
            #pragma unroll
            for (int dx = -1; dx <= 1; ++dx) {
                int xx = x + dx;
                if (xx < 0 || xx > 31) continue;
                uint4 u = *(const uint4*)(base + (size_t)(yy * 32 + xx) * 1024 + ch0);
                int tap = (dy + 1) * 3 + (dx + 1);
                acc[0] += lo16f(u.x) * w[tap][0];
                acc[1] += hi16f(u.x) * w[tap][1];
                acc[2] += lo16f(u.y) * w[tap][2];
                acc[3] += hi16f(u.y) * w[tap][3];
                acc[4] += lo16f(u.z) * w[tap][4];
                acc[5] += hi16f(u.z) * w[tap][5];
                acc[6] += lo16f(u.w) * w[tap][6];
                acc[7] += hi16f(u.w) * w[tap][7];
            }
        }
        unsigned short r[8];
        #pragma unroll
        for (int c = 0; c < 8; ++c)
            r[c] = f2b(gelu_f(acc[c] * sc[c] + sh[c]));
        uint4 o;
        o.x = (unsigned)r[0] | ((unsigned)r[1] << 16);
        o.y = (unsigned)r[2] | ((unsigned)r[3] << 16);
        o.z = (unsigned)r[4] | ((unsigned)r[5] << 16);
        o.w = (unsigned)r[6] | ((unsigned)r[7] << 16);
        *(uint4*)(ob + (size_t)(y * 32 + x) * 1024 + ch0) = o;
    }
}

// ---------------------------------------------------------------- NHWC f32 -> NCHW f32 (final)
__global__ __launch_bounds__(256) void trout_k(const float* __restrict__ y,
                                               float* __restrict__ out) {
    __shared__ float tile[64][65];
    int hw0 = blockIdx.x * 64, c0 = blockIdx.y * 64, b = blockIdx.z;
    int t = threadIdx.x;
    #pragma unroll
    for (int r = 0; r < 16; ++r) {
        int hl = r * 4 + (t >> 6);
        tile[t & 63][hl] = y[((size_t)(b * 1024 + hw0 + hl)) * 256 + c0 + (t & 63)];
    }
    __syncthreads();
    #pragma unroll
    for (int r = 0; r < 16; ++r) {
        int cl = r * 4 + (t >> 6);
        out[((size_t)(b * 256 + c0 + cl)) * 1024 + hw0 + (t & 63)] = tile[cl][t & 63];
    }
}

// ---------------------------------------------------------------- launch
extern "C" void kernel_launch(void* const* d_in, const int* in_sizes, int n_in,
                              void* d_out, int out_size, void* d_ws, size_t ws_size,
                              hipStream_t stream) {
    const float* x      = (const float*)d_in[0];
    const float* bn0_g  = (const float*)d_in[1];
    const float* bn0_b  = (const float*)d_in[2];
    const float* bn0_m  = (const float*)d_in[3];
    const float* bn0_v  = (const float*)d_in[4];
    const float* w_qkv  = (const float*)d_in[5];
    const float* w_merge= (const float*)d_in[6];
    const float* b_merge= (const float*)d_in[7];
    const float* w1     = (const float*)d_in[8];
    const float* bn1_g  = (const float*)d_in[9];
    const float* bn1_b  = (const float*)d_in[10];
    const float* bn1_m  = (const float*)d_in[11];
    const float* bn1_v  = (const float*)d_in[12];
    const float* dw     = (const float*)d_in[13];
    const float* bn2_g  = (const float*)d_in[14];
    const float* bn2_b  = (const float*)d_in[15];
    const float* bn2_m  = (const float*)d_in[16];
    const float* bn2_v  = (const float*)d_in[17];
    const float* w2     = (const float*)d_in[18];
    const float* bn3_g  = (const float*)d_in[19];
    const float* bn3_b  = (const float*)d_in[20];
    const float* bn3_m  = (const float*)d_in[21];
    const float* bn3_v  = (const float*)d_in[22];
    float* out = (float*)d_out;

    char* w = (char*)d_ws;
    unsigned short* h0b   = (unsigned short*)(w);                // [b][hw][256] bf16
    unsigned short* qkvb  = (unsigned short*)(w + 8388608);      // [b][hw][768] bf16
    unsigned short* msgb  = (unsigned short*)(w + 33554432);     // [b][hw][256] bf16
    unsigned short* xrb   = (unsigned short*)(w + 41943040);     // [b][hw][256] bf16
    unsigned short* h1b   = (unsigned short*)(w + 50331648);     // [b][hw][1024] bf16
    unsigned short* h2b   = (unsigned short*)(w + 83886080);     // [b][hw][1024] bf16
    float*  xt    = (float*)(w + 117440512);                     // [b][hw][256] f32 (raw x)
    float*  xrf   = (float*)(w + 134217728);                     // [b][hw][256] f32
    float*  yf    = (float*)(w + 150994944);                     // [b][hw][256] f32
    float*  hm    = (float*)(w + 167772160);                     // [b][64][256] f32
    unsigned short* wqkvb = (unsigned short*)(w + 168820736);
    unsigned short* wmrgb = (unsigned short*)(w + 169213952);
    unsigned short* w1b   = (unsigned short*)(w + 169345024);
    unsigned short* w2b   = (unsigned short*)(w + 169869312);
    int*    idx   = (int*)(w + 170393600);                       // 131072 B
    float*  wtbuf = (float*)(w + 170524672);                     // 9*1024 f32
    float*  scbuf = (float*)(w + 170561536);                     // 1024 f32
    float*  shbuf = (float*)(w + 170565632);                     // 1024 f32
    float*  qkdbuf= (float*)(w + 170569728);                     // [1024][512] f32 (2 MB)

    // weights -> bf16 + dw prep
    wcvt_k<<<192, 256, 0, stream>>>(w_qkv, wqkvb, 49152);
    wcvt_k<<<64,  256, 0, stream>>>(w_merge, wmrgb, 16384);
    wcvt_k<<<256, 256, 0, stream>>>(w1, w1b, 65536);
    wcvt_k<<<256, 256, 0, stream>>>(w2, w2b, 65536);
    wprep_k<<<4, 256, 0, stream>>>(dw, bn2_g, bn2_b, bn2_m, bn2_v, wtbuf, scbuf, shbuf);

    // bn0+gelu + transpose to NHWC
    bn0tr_k<<<dim3(16, 4, 16), 256, 0, stream>>>(x, bn0_g, bn0_b, bn0_m, bn0_v, h0b, xt);
    // exact f32 window means
    hm_k<<<1024, 256, 0, stream>>>(xt, bn0_g, bn0_b, bn0_m, bn0_v, hm);
    // qkv = w_qkv @ h0
    mgemm<0><<<dim3(8, 6, 16), 256, 0, stream>>>(wqkvb, h0b, qkvb, nullptr,
        nullptr, nullptr, nullptr, nullptr, nullptr, 768, 256);
    // descriptors (tiled f32 GEMM) + top-k
    desc2_k<<<dim3(16, 8), 256, 0, stream>>>(hm, w_qkv, qkdbuf);
    aff_k<<<128, 256, 0, stream>>>(qkdbuf, idx);
    // attention
    attn_k<<<8192, 256, 0, stream>>>(qkvb, idx, msgb);
    // xr = x + w_merge@msg + bias
    mgemm<1><<<dim3(8, 2, 16), 256, 0, stream>>>(wmrgb, msgb, xrb, xrf,
        xt, b_merge, nullptr, nullptr, nullptr, 256, 256);
    // h1 = gelu(bn1(w1@xr))
    mgemm<2><<<dim3(8, 8, 16), 256, 0, stream>>>(w1b, xrb, h1b, nullptr,
        nullptr, bn1_g, bn1_b, bn1_m, bn1_v, 1024, 256);
    // h2 = gelu(bn2(dw3x3(h1)))  — vectorized
    dw_k<<<2048, 256, 0, stream>>>(h1b, wtbuf, scbuf, shbuf, h2b);
    // y = bn3(w2@h2) + xr  (f32 NHWC)
    mgemm<3><<<dim3(8, 2, 16), 256, 0, stream>>>(w2b, h2b, nullptr, yf,
        xrf, bn3_g, bn3_b, bn3_m, bn3_v, 256, 1024);
    // NHWC -> NCHW
    trout_k<<<dim3(16, 4, 16), 256, 0, stream>>>(yf, out);
}

// Round 11
// 370.830 us; speedup vs baseline: 1.2109x; 1.0184x over previous
//
#include <hip/hip_runtime.h>
#include <hip/hip_bf16.h>

#define EPSV 1e-5f

typedef short bf16x8 __attribute__((ext_vector_type(8)));
typedef float f32x4 __attribute__((ext_vector_type(4)));

__device__ __forceinline__ float gelu_f(float x) {
    return 0.5f * x * (1.0f + erff(x * 0.70710678118654752f));
}
__device__ __forceinline__ float b2f(unsigned short u) {
    union { float f; unsigned i; } c; c.i = ((unsigned)u) << 16; return c.f;
}
__device__ __forceinline__ unsigned short f2b(float f) {
    __hip_bfloat16 h = __float2bfloat16(f);
    return *reinterpret_cast<unsigned short*>(&h);
}
__device__ __forceinline__ float lo16f(unsigned v) {
    union { float f; unsigned i; } c; c.i = v << 16; return c.f;
}
__device__ __forceinline__ float hi16f(unsigned v) {
    union { float f; unsigned i; } c; c.i = v & 0xffff0000u; return c.f;
}
// async global->LDS, 16B per lane; LDS dest = wave-uniform base + lane*16
__device__ __forceinline__ void gload16(const unsigned short* g, unsigned short* l) {
    __builtin_amdgcn_global_load_lds(
        (const __attribute__((address_space(1))) void*)g,
        (__attribute__((address_space(3))) void*)l, 16, 0, 0);
}

// ---------------------------------------------------------------- weight f32->bf16
__global__ __launch_bounds__(256) void wcvt_k(const float* __restrict__ w,
                                              unsigned short* __restrict__ o, int n4) {
    int i = blockIdx.x * 256 + threadIdx.x;
    if (i >= n4) return;
    float4 v = ((const float4*)w)[i];
    ushort4 u = make_ushort4(f2b(v.x), f2b(v.y), f2b(v.z), f2b(v.w));
    ((ushort4*)o)[i] = u;
}

// ---------------------------------------------------------------- dw weight transpose + bn2 fold
__global__ __launch_bounds__(256) void wprep_k(const float* __restrict__ wdw,
    const float* __restrict__ g, const float* __restrict__ bt,
    const float* __restrict__ mu, const float* __restrict__ va,
    float* __restrict__ wt, float* __restrict__ scf, float* __restrict__ shf) {
    int ch = blockIdx.x * 256 + threadIdx.x;   // 1024 total
    #pragma unroll
    for (int tap = 0; tap < 9; ++tap)
        wt[tap * 1024 + ch] = wdw[ch * 9 + tap];
    float s = g[ch] * rsqrtf(va[ch] + EPSV);
    scf[ch] = s;
    shf[ch] = bt[ch] - mu[ch] * s;
}

// ---------------------------------------------------------------- bn0+gelu + NCHW->NHWC
__global__ __launch_bounds__(256) void bn0tr_k(const float* __restrict__ x,
    const float* __restrict__ g, const float* __restrict__ bt,
    const float* __restrict__ mu, const float* __restrict__ va,
    unsigned short* __restrict__ h0b, float* __restrict__ xt) {
    __shared__ float tile[64][65];
    int hw0 = blockIdx.x * 64, c0 = blockIdx.y * 64, b = blockIdx.z;
    int t = threadIdx.x;
    int cl = t >> 6, hl = t & 63;
    #pragma unroll
    for (int r = 0; r < 16; ++r)
        tile[r * 4 + cl][hl] = x[((size_t)(b * 256 + c0 + r * 4 + cl)) * 1024 + hw0 + hl];
    __syncthreads();
    int c = c0 + (t & 63);
    float s = g[c] * rsqrtf(va[c] + EPSV);
    float m_ = mu[c], be = bt[c];
    #pragma unroll
    for (int r = 0; r < 16; ++r) {
        int hl2 = r * 4 + (t >> 6);
        float v = tile[t & 63][hl2];
        size_t o = ((size_t)(b * 1024 + hw0 + hl2)) * 256 + c;
        xt[o] = v;
        h0b[o] = f2b(gelu_f((v - m_) * s + be));
    }
}

// ---------------------------------------------------------------- per-window mean of gelu(bn0(x)), f32 (exact)
__global__ __launch_bounds__(256) void hm_k(const float* __restrict__ xt,
    const float* __restrict__ g, const float* __restrict__ bt,
    const float* __restrict__ mu, const float* __restrict__ va,
    float* __restrict__ hm) {
    int blk = blockIdx.x;           // b*64 + win
    int b = blk >> 6, win = blk & 63;
    int c = threadIdx.x;
    int base = (win >> 3) * 128 + (win & 7) * 4;
    float s = g[c] * rsqrtf(va[c] + EPSV);
    float m_ = mu[c], be = bt[c];
    float acc = 0.f;
    #pragma unroll
    for (int ty = 0; ty < 4; ++ty)
        #pragma unroll
        for (int tx = 0; tx < 4; ++tx) {
            float v = xt[((size_t)(b * 1024 + base + ty * 32 + tx)) * 256 + c];
            acc += gelu_f((v - m_) * s + be);
        }
    hm[(size_t)blk * 256 + c] = acc * (1.f / 16.f);
}

// ---------------------------------------------------------------- MFMA GEMM, 128x128 tile, BK=32
template <int MODE>
__global__ __launch_bounds__(256) void mgemm(
    const unsigned short* __restrict__ A, const unsigned short* __restrict__ X,
    unsigned short* __restrict__ outb, float* __restrict__ outf,
    const float* __restrict__ res,
    const float* __restrict__ p0, const float* __restrict__ p1,
    const float* __restrict__ p2, const float* __restrict__ p3,
    int M, int Kd) {
    __shared__ __align__(16) unsigned short As[4096];   // [128 m][32 k]
    __shared__ __align__(16) unsigned short Bs[4096];   // [128 n][32 k]
    const int t = threadIdx.x;
    const int wid = t >> 6, lane = t & 63;
    const int n0 = blockIdx.x * 128, m0 = blockIdx.y * 128, b = blockIdx.z;
    const unsigned short* Ab = A + (size_t)m0 * Kd;
    const unsigned short* Xb = X + ((size_t)b * 1024 + n0) * Kd;

    const int srow = lane >> 2;
    const int skb  = (lane & 3) * 8;
    const int wr = wid >> 1, wc = wid & 1;
    const int lr = lane & 15;
    const int lk = (lane >> 4) * 8;

    f32x4 acc[4][4] = {};

    for (int k0 = 0; k0 < Kd; k0 += 32) {
        #pragma unroll
        for (int i = 0; i < 2; ++i) {
            int chunk = wid * 2 + i;
            int row = chunk * 16 + srow;
            gload16(Ab + (size_t)row * Kd + k0 + skb, &As[chunk * 512]);
            gload16(Xb + (size_t)row * Kd + k0 + skb, &Bs[chunk * 512]);
        }
        __syncthreads();
        bf16x8 af[4], bfv[4];
        #pragma unroll
        for (int mi = 0; mi < 4; ++mi)
            af[mi] = *(const bf16x8*)&As[(wr * 64 + mi * 16 + lr) * 32 + lk];
        #pragma unroll
        for (int ni = 0; ni < 4; ++ni)
            bfv[ni] = *(const bf16x8*)&Bs[(wc * 64 + ni * 16 + lr) * 32 + lk];
        #pragma unroll
        for (int mi = 0; mi < 4; ++mi)
            #pragma unroll
            for (int ni = 0; ni < 4; ++ni)
                acc[mi][ni] = __builtin_amdgcn_mfma_f32_16x16x32_bf16(
                    af[mi], bfv[ni], acc[mi][ni], 0, 0, 0);
        __syncthreads();
    }

    const int crow = (lane >> 4) * 4;
    #pragma unroll
    for (int ni = 0; ni < 4; ++ni) {
        const int n = n0 + wc * 64 + ni * 16 + lr;
        #pragma unroll
        for (int mi = 0; mi < 4; ++mi) {
            const int m = m0 + wr * 64 + mi * 16 + crow;
            f32x4 v = acc[mi][ni];
            size_t o = ((size_t)b * 1024 + n) * (size_t)M + m;
            if (MODE == 0) {
                *(ushort4*)(outb + o) = make_ushort4(f2b(v[0]), f2b(v[1]), f2b(v[2]), f2b(v[3]));
            } else if (MODE == 1) {
                float4 r = *(const float4*)(res + o);
                float4 bi = *(const float4*)(p0 + m);
                float w0 = v[0] + r.x + bi.x, w1 = v[1] + r.y + bi.y;
                float w2 = v[2] + r.z + bi.z, w3 = v[3] + r.w + bi.w;
                *(float4*)(outf + o) = make_float4(w0, w1, w2, w3);
                *(ushort4*)(outb + o) = make_ushort4(f2b(w0), f2b(w1), f2b(w2), f2b(w3));
            } else if (MODE == 2) {
                float4 gg = *(const float4*)(p0 + m);
                float4 be = *(const float4*)(p1 + m);
                float4 mm = *(const float4*)(p2 + m);
                float4 vv = *(const float4*)(p3 + m);
                float h0 = gelu_f((v[0] - mm.x) * (gg.x * rsqrtf(vv.x + EPSV)) + be.x);
                float h1 = gelu_f((v[1] - mm.y) * (gg.y * rsqrtf(vv.y + EPSV)) + be.y);
                float h2 = gelu_f((v[2] - mm.z) * (gg.z * rsqrtf(vv.z + EPSV)) + be.z);
                float h3 = gelu_f((v[3] - mm.w) * (gg.w * rsqrtf(vv.w + EPSV)) + be.w);
                *(ushort4*)(outb + o) = make_ushort4(f2b(h0), f2b(h1), f2b(h2), f2b(h3));
            } else {
                float4 gg = *(const float4*)(p0 + m);
                float4 be = *(const float4*)(p1 + m);
                float4 mm = *(const float4*)(p2 + m);
                float4 vv = *(const float4*)(p3 + m);
                float4 r = *(const float4*)(res + o);
                float y0 = (v[0] - mm.x) * (gg.x * rsqrtf(vv.x + EPSV)) + be.x + r.x;
                float y1 = (v[1] - mm.y) * (gg.y * rsqrtf(vv.y + EPSV)) + be.y + r.y;
                float y2 = (v[2] - mm.z) * (gg.z * rsqrtf(vv.z + EPSV)) + be.z + r.z;
                float y3 = (v[3] - mm.w) * (gg.w * rsqrtf(vv.w + EPSV)) + be.w + r.w;
                *(float4*)(outf + o) = make_float4(y0, y1, y2, y3);
            }
        }
    }
}

// ---------------------------------------------------------------- descriptor GEMM (f32 exact, tiled)
__global__ __launch_bounds__(256) void desc2_k(const float* __restrict__ hm,
                                               const float* __restrict__ w_qkv,
                                               float* __restrict__ qkd) {
    __shared__ float As[16][64];   // [k][o]
    __shared__ float Bs[16][64];   // [k][row]
    float acc[4][4] = {{0.f}};
    const int t = threadIdx.x;
    const int tn = t & 15, tm = t >> 4;
    const int n0 = blockIdx.x * 64;   // row tile
    const int m0 = blockIdx.y * 64;   // output tile
    for (int k0 = 0; k0 < 256; k0 += 16) {
        {
            int r  = t >> 2;
            int k4 = (t & 3) << 2;
            float4 a4 = *(const float4*)(w_qkv + (size_t)(m0 + r) * 256 + k0 + k4);
            As[k4 + 0][r] = a4.x; As[k4 + 1][r] = a4.y;
            As[k4 + 2][r] = a4.z; As[k4 + 3][r] = a4.w;
            float4 b4 = *(const float4*)(hm + (size_t)(n0 + r) * 256 + k0 + k4);
            Bs[k4 + 0][r] = b4.x; Bs[k4 + 1][r] = b4.y;
            Bs[k4 + 2][r] = b4.z; Bs[k4 + 3][r] = b4.w;
        }
        __syncthreads();
        #pragma unroll
        for (int kk = 0; kk < 16; ++kk) {
            float4 av = *(const float4*)&As[kk][tm << 2];
            float4 bv = *(const float4*)&Bs[kk][tn << 2];
            float a0[4] = {av.x, av.y, av.z, av.w};
            float b0[4] = {bv.x, bv.y, bv.z, bv.w};
            #pragma unroll
            for (int i = 0; i < 4; ++i)
                #pragma unroll
                for (int j = 0; j < 4; ++j)
                    acc[i][j] += a0[i] * b0[j];
        }
        __syncthreads();
    }
    #pragma unroll
    for (int j = 0; j < 4; ++j) {
        int row = n0 + (tn << 2) + j;
        float4 v = make_float4(acc[0][j], acc[1][j], acc[2][j], acc[3][j]);
        *(float4*)(qkd + (size_t)row * 512 + m0 + (tm << 2)) = v;
    }
}

// ---------------------------------------------------------------- affinity + top-4 per (b,h)
__global__ __launch_bounds__(256) void aff_k(const float* __restrict__ qkd,
                                             int* __restrict__ idx_out) {
    int bh = blockIdx.x;            // b*8 + h (128)
    int b = bh >> 3, h = bh & 7;
    __shared__ float qdl[64][33];
    __shared__ float kdl[64][33];
    __shared__ float wsc[64][65];
    int t = threadIdx.x;
    for (int e = t; e < 2048; e += 256) {
        int wn = e >> 5, d = e & 31;
        size_t src = ((size_t)(b * 64 + wn)) * 512 + h * 32 + d;
        qdl[wn][d] = qkd[src];
        kdl[wn][d] = qkd[src + 256];
    }
    __syncthreads();
    {
        int i = t >> 2, j0 = (t & 3) * 16;
        float s[16];
        #pragma unroll
        for (int j = 0; j < 16; ++j) s[j] = 0.f;
        #pragma unroll
        for (int d = 0; d < 32; ++d) {
            float qv = qdl[i][d];
            #pragma unroll
            for (int j = 0; j < 16; ++j) s[j] += qv * kdl[j0 + j][d];
        }
        #pragma unroll
        for (int j = 0; j < 16; ++j) wsc[i][j0 + j] = s[j];
    }
    __syncthreads();
    if (t < 64) {
        float bv[4] = {-1e30f, -1e30f, -1e30f, -1e30f};
        int   bi[4] = {0, 0, 0, 0};
        for (int j = 0; j < 64; ++j) {
            float v = wsc[t][j];
            if (v > bv[3]) {
                int p = 3;
                while (p > 0 && v > bv[p - 1]) {
                    bv[p] = bv[p - 1]; bi[p] = bi[p - 1]; --p;
                }
                bv[p] = v; bi[p] = j;
            }
        }
        int* o = idx_out + (bh * 64 + t) * 4;
        o[0] = bi[0]; o[1] = bi[1]; o[2] = bi[2]; o[3] = bi[3];
    }
}

// ---------------------------------------------------------------- gathered window attention (NHWC bf16)
// Bank-conflict-free: padded LDS, register-tiled QK^T and PV, vectorized gather.
// Math is bit-identical to the previous version (same summation orders).
__global__ __launch_bounds__(256) void attn_k(const unsigned short* __restrict__ qkv,
                                              const int* __restrict__ idx,
                                              unsigned short* __restrict__ msg) {
    int blk = blockIdx.x;
    int win = blk & 63;
    int bh = blk >> 6;
    int b = bh >> 3, h = bh & 7;
    __shared__ float qs[16][33];
    __shared__ float ks[64][33];
    __shared__ float vs[64][33];
    __shared__ float sc[16][65];
    __shared__ int widx[4];
    int t = threadIdx.x;
    if (t < 4) widx[t] = idx[(bh * 64 + win) * 4 + t];
    __syncthreads();
    int qb = (win >> 3) * 128 + (win & 7) * 4;

    // --- gather Q (16 tok x 32 d), uint2 = 4 bf16 per load
    if (t < 128) {
        int tok = t >> 3, d4 = (t & 7) * 4;
        int hw = qb + (tok >> 2) * 32 + (tok & 3);
        uint2 u = *(const uint2*)&qkv[((size_t)(b * 1024 + hw)) * 768 + h * 32 + d4];
        qs[tok][d4 + 0] = lo16f(u.x); qs[tok][d4 + 1] = hi16f(u.x);
        qs[tok][d4 + 2] = lo16f(u.y); qs[tok][d4 + 3] = hi16f(u.y);
    }
    // --- gather K,V (64 keys x 32 d each)
    for (int e = t; e < 512; e += 256) {
        int key = e >> 3, d4 = (e & 7) * 4;
        int wsel = widx[key >> 4];
        int tok = key & 15;
        int hw = (wsel >> 3) * 128 + (wsel & 7) * 4 + (tok >> 2) * 32 + (tok & 3);
        size_t base = ((size_t)(b * 1024 + hw)) * 768 + h * 32 + d4;
        uint2 uk = *(const uint2*)&qkv[base + 256];
        uint2 uv = *(const uint2*)&qkv[base + 512];
        ks[key][d4 + 0] = lo16f(uk.x); ks[key][d4 + 1] = hi16f(uk.x);
        ks[key][d4 + 2] = lo16f(uk.y); ks[key][d4 + 3] = hi16f(uk.y);
        vs[key][d4 + 0] = lo16f(uv.x); vs[key][d4 + 1] = hi16f(uv.x);
        vs[key][d4 + 2] = lo16f(uv.y); vs[key][d4 + 3] = hi16f(uv.y);
    }
    __syncthreads();

    const float scale = 0.17677669529663688f;
    // --- QK^T: thread = (row r, key-group cg of 4); q broadcast, 4 accumulators
    {
        int r = t & 15, cg = t >> 4;
        int c0 = cg * 4;
        float s0 = 0.f, s1 = 0.f, s2 = 0.f, s3 = 0.f;
        #pragma unroll
        for (int d = 0; d < 32; ++d) {
            float qv = qs[r][d];
            s0 += qv * ks[c0 + 0][d];
            s1 += qv * ks[c0 + 1][d];
            s2 += qv * ks[c0 + 2][d];
            s3 += qv * ks[c0 + 3][d];
        }
        sc[r][c0 + 0] = s0 * scale;
        sc[r][c0 + 1] = s1 * scale;
        sc[r][c0 + 2] = s2 * scale;
        sc[r][c0 + 3] = s3 * scale;
    }
    __syncthreads();
    {   // softmax over 64: 16 rows x 16 lanes, 4 cols each (unchanged math)
        int r = t >> 4, c0 = (t & 15) << 2;
        float v0 = sc[r][c0], v1 = sc[r][c0 + 1], v2 = sc[r][c0 + 2], v3 = sc[r][c0 + 3];
        float mx = fmaxf(fmaxf(v0, v1), fmaxf(v2, v3));
        #pragma unroll
        for (int m = 1; m < 16; m <<= 1) mx = fmaxf(mx, __shfl_xor(mx, m));
        float e0 = expf(v0 - mx), e1 = expf(v1 - mx), e2 = expf(v2 - mx), e3 = expf(v3 - mx);
        float sm = e0 + e1 + e2 + e3;
        #pragma unroll
        for (int m = 1; m < 16; m <<= 1) sm += __shfl_xor(sm, m);
        float inv = 1.0f / sm;
        sc[r][c0] = e0 * inv; sc[r][c0 + 1] = e1 * inv;
        sc[r][c0 + 2] = e2 * inv; sc[r][c0 + 3] = e3 * inv;
    }
    __syncthreads();
    // --- PV: thread = (tok, 2 d's); p broadcast, packed u32 store
    {
        int tok = t >> 4, d0 = (t & 15) * 2;
        float a0 = 0.f, a1 = 0.f;
        #pragma unroll
        for (int kk = 0; kk < 64; ++kk) {
            float p = sc[tok][kk];
            a0 += p * vs[kk][d0];
            a1 += p * vs[kk][d0 + 1];
        }
        int hw = qb + (tok >> 2) * 32 + (tok & 3);
        unsigned pack = (unsigned)f2b(a0) | ((unsigned)f2b(a1) << 16);
        *(unsigned*)&msg[((size_t)(b * 1024 + hw)) * 256 + h * 32 + d0] = pack;
    }
}

// ---------------------------------------------------------------- K5: depthwise 3x3 + bn2 + gelu, vectorized
__global__ __launch_bounds__(256) void dw_k(const unsigned short* __restrict__ h1,
    const float* __restrict__ wt, const float* __restrict__ scf,
    const float* __restrict__ shf, unsigned short* __restrict__ h2) {
    int t = threadIdx.x;
    int c8 = t & 127;             // channel octet 0..127
    int pl = t >> 7;              // 0/1
    int blk = blockIdx.x;         // 2048 total: b(16) * y(32) * xg(4)
    int b = blk >> 7;
    int rem = blk & 127;
    int y = rem >> 2;
    int x0 = (rem & 3) * 8;
    int ch0 = c8 * 8;

    float w[9][8];
    #pragma unroll
    for (int tap = 0; tap < 9; ++tap) {
        float4 a = *(const float4*)(wt + tap * 1024 + ch0);
        float4 bq = *(const float4*)(wt + tap * 1024 + ch0 + 4);
        w[tap][0] = a.x; w[tap][1] = a.y; w[tap][2] = a.z; w[tap][3] = a.w;
        w[tap][4] = bq.x; w[tap][5] = bq.y; w[tap][6] = bq.z; w[tap][7] = bq.w;
    }
    float sc[8], sh[8];
    {
        float4 a = *(const float4*)(scf + ch0);
        float4 bq = *(const float4*)(scf + ch0 + 4);
        sc[0]=a.x; sc[1]=a.y; sc[2]=a.z; sc[3]=a.w; sc[4]=bq.x; sc[5]=bq.y; sc[6]=bq.z; sc[7]=bq.w;
        float4 c = *(const float4*)(shf + ch0);
        float4 dq = *(const float4*)(shf + ch0 + 4);
        sh[0]=c.x; sh[1]=c.y; sh[2]=c.z; sh[3]=c.w; sh[4]=dq.x; sh[5]=dq.y; sh[6]=dq.z; sh[7]=dq.w;
    }

    const unsigned short* base = h1 + (size_t)b * 1048576;
    unsigned short* ob = h2 + (size_t)b * 1048576;

    #pragma unroll
    for (int j = 0; j < 4; ++j) {
        int x = x0 + pl + 2 * j;
        float acc[8] = {0.f,0.f,0.f,0.f,0.f,0.f,0.f,0.f};
        #pragma unroll
        for (int dy = -1; dy <= 1; ++dy) {
            int yy = y + dy;
            if (yy < 0 || yy > 31) continue;
            #pragma unroll
            for (int dx = -1; dx <= 1; ++dx) {
                int xx = x + dx;
                if (xx < 0 || xx > 31) continue;
                uint4 u = *(const uint4*)(base + (size_t)(yy * 32 + xx) * 1024 + ch0);
                int tap = (dy + 1) * 3 + (dx + 1);
                acc[0] += lo16f(u.x) * w[tap][0];
                acc[1] += hi16f(u.x) * w[tap][1];
                acc[2] += lo16f(u.y) * w[tap][2];
                acc[3] += hi16f(u.y) * w[tap][3];
                acc[4] += lo16f(u.z) * w[tap][4];
                acc[5] += hi16f(u.z) * w[tap][5];
                acc[6] += lo16f(u.w) * w[tap][6];
                acc[7] += hi16f(u.w) * w[tap][7];
            }
        }
        unsigned short r[8];
        #pragma unroll
        for (int c = 0; c < 8; ++c)
            r[c] = f2b(gelu_f(acc[c] * sc[c] + sh[c]));
        uint4 o;
        o.x = (unsigned)r[0] | ((unsigned)r[1] << 16);
        o.y = (unsigned)r[2] | ((unsigned)r[3] << 16);
        o.z = (unsigned)r[4] | ((unsigned)r[5] << 16);
        o.w = (unsigned)r[6] | ((unsigned)r[7] << 16);
        *(uint4*)(ob + (size_t)(y * 32 + x) * 1024 + ch0) = o;
    }
}

// ---------------------------------------------------------------- NHWC f32 -> NCHW f32 (final)
__global__ __launch_bounds__(256) void trout_k(const float* __restrict__ y,
                                               float* __restrict__ out) {
    __shared__ float tile[64][65];
    int hw0 = blockIdx.x * 64, c0 = blockIdx.y * 64, b = blockIdx.z;
    int t = threadIdx.x;
    #pragma unroll
    for (int r = 0; r < 16; ++r) {
        int hl = r * 4 + (t >> 6);
        tile[t & 63][hl] = y[((size_t)(b * 1024 + hw0 + hl)) * 256 + c0 + (t & 63)];
    }
    __syncthreads();
    #pragma unroll
    for (int r = 0; r < 16; ++r) {
        int cl = r * 4 + (t >> 6);
        out[((size_t)(b * 256 + c0 + cl)) * 1024 + hw0 + (t & 63)] = tile[cl][t & 63];
    }
}

// ---------------------------------------------------------------- launch
extern "C" void kernel_launch(void* const* d_in, const int* in_sizes, int n_in,
                              void* d_out, int out_size, void* d_ws, size_t ws_size,
                              hipStream_t stream) {
    const float* x      = (const float*)d_in[0];
    const float* bn0_g  = (const float*)d_in[1];
    const float* bn0_b  = (const float*)d_in[2];
    const float* bn0_m  = (const float*)d_in[3];
    const float* bn0_v  = (const float*)d_in[4];
    const float* w_qkv  = (const float*)d_in[5];
    const float* w_merge= (const float*)d_in[6];
    const float* b_merge= (const float*)d_in[7];
    const float* w1     = (const float*)d_in[8];
    const float* bn1_g  = (const float*)d_in[9];
    const float* bn1_b  = (const float*)d_in[10];
    const float* bn1_m  = (const float*)d_in[11];
    const float* bn1_v  = (const float*)d_in[12];
    const float* dw     = (const float*)d_in[13];
    const float* bn2_g  = (const float*)d_in[14];
    const float* bn2_b  = (const float*)d_in[15];
    const float* bn2_m  = (const float*)d_in[16];
    const float* bn2_v  = (const float*)d_in[17];
    const float* w2     = (const float*)d_in[18];
    const float* bn3_g  = (const float*)d_in[19];
    const float* bn3_b  = (const float*)d_in[20];
    const float* bn3_m  = (const float*)d_in[21];
    const float* bn3_v  = (const float*)d_in[22];
    float* out = (float*)d_out;

    char* w = (char*)d_ws;
    unsigned short* h0b   = (unsigned short*)(w);                // [b][hw][256] bf16
    unsigned short* qkvb  = (unsigned short*)(w + 8388608);      // [b][hw][768] bf16
    unsigned short* msgb  = (unsigned short*)(w + 33554432);     // [b][hw][256] bf16
    unsigned short* xrb   = (unsigned short*)(w + 41943040);     // [b][hw][256] bf16
    unsigned short* h1b   = (unsigned short*)(w + 50331648);     // [b][hw][1024] bf16
    unsigned short* h2b   = (unsigned short*)(w + 83886080);     // [b][hw][1024] bf16
    float*  xt    = (float*)(w + 117440512);                     // [b][hw][256] f32 (raw x)
    float*  xrf   = (float*)(w + 134217728);                     // [b][hw][256] f32
    float*  yf    = (float*)(w + 150994944);                     // [b][hw][256] f32
    float*  hm    = (float*)(w + 167772160);                     // [b][64][256] f32
    unsigned short* wqkvb = (unsigned short*)(w + 168820736);
    unsigned short* wmrgb = (unsigned short*)(w + 169213952);
    unsigned short* w1b   = (unsigned short*)(w + 169345024);
    unsigned short* w2b   = (unsigned short*)(w + 169869312);
    int*    idx   = (int*)(w + 170393600);                       // 131072 B
    float*  wtbuf = (float*)(w + 170524672);                     // 9*1024 f32
    float*  scbuf = (float*)(w + 170561536);                     // 1024 f32
    float*  shbuf = (float*)(w + 170565632);                     // 1024 f32
    float*  qkdbuf= (float*)(w + 170569728);                     // [1024][512] f32 (2 MB)

    // weights -> bf16 + dw prep
    wcvt_k<<<192, 256, 0, stream>>>(w_qkv, wqkvb, 49152);
    wcvt_k<<<64,  256, 0, stream>>>(w_merge, wmrgb, 16384);
    wcvt_k<<<256, 256, 0, stream>>>(w1, w1b, 65536);
    wcvt_k<<<256, 256, 0, stream>>>(w2, w2b, 65536);
    wprep_k<<<4, 256, 0, stream>>>(dw, bn2_g, bn2_b, bn2_m, bn2_v, wtbuf, scbuf, shbuf);

    // bn0+gelu + transpose to NHWC
    bn0tr_k<<<dim3(16, 4, 16), 256, 0, stream>>>(x, bn0_g, bn0_b, bn0_m, bn0_v, h0b, xt);
    // exact f32 window means
    hm_k<<<1024, 256, 0, stream>>>(xt, bn0_g, bn0_b, bn0_m, bn0_v, hm);
    // qkv = w_qkv @ h0
    mgemm<0><<<dim3(8, 6, 16), 256, 0, stream>>>(wqkvb, h0b, qkvb, nullptr,
        nullptr, nullptr, nullptr, nullptr, nullptr, 768, 256);
    // descriptors (tiled f32 GEMM) + top-k
    desc2_k<<<dim3(16, 8), 256, 0, stream>>>(hm, w_qkv, qkdbuf);
    aff_k<<<128, 256, 0, stream>>>(qkdbuf, idx);
    // attention
    attn_k<<<8192, 256, 0, stream>>>(qkvb, idx, msgb);
    // xr = x + w_merge@msg + bias
    mgemm<1><<<dim3(8, 2, 16), 256, 0, stream>>>(wmrgb, msgb, xrb, xrf,
        xt, b_merge, nullptr, nullptr, nullptr, 256, 256);
    // h1 = gelu(bn1(w1@xr))
    mgemm<2><<<dim3(8, 8, 16), 256, 0, stream>>>(w1b, xrb, h1b, nullptr,
        nullptr, bn1_g, bn1_b, bn1_m, bn1_v, 1024, 256);
    // h2 = gelu(bn2(dw3x3(h1)))  — vectorized
    dw_k<<<2048, 256, 0, stream>>>(h1b, wtbuf, scbuf, shbuf, h2b);
    // y = bn3(w2@h2) + xr  (f32 NHWC)
    mgemm<3><<<dim3(8, 2, 16), 256, 0, stream>>>(w2b, h2b, nullptr, yf,
        xrf, bn3_g, bn3_b, bn3_m, bn3_v, 256, 1024);
    // NHWC -> NCHW
    trout_k<<<dim3(16, 4, 16), 256, 0, stream>>>(yf, out);
}

// Round 12
// 345.207 us; speedup vs baseline: 1.3008x; 1.0742x over previous
//
#include <hip/hip_runtime.h>
#include <hip/hip_bf16.h>

#define EPSV 1e-5f

typedef short bf16x8 __attribute__((ext_vector_type(8)));
typedef float f32x4 __attribute__((ext_vector_type(4)));

__device__ __forceinline__ float gelu_f(float x) {
    return 0.5f * x * (1.0f + erff(x * 0.70710678118654752f));
}
__device__ __forceinline__ float b2f(unsigned short u) {
    union { float f; unsigned i; } c; c.i = ((unsigned)u) << 16; return c.f;
}
__device__ __forceinline__ unsigned short f2b(float f) {
    __hip_bfloat16 h = __float2bfloat16(f);
    return *reinterpret_cast<unsigned short*>(&h);
}
__device__ __forceinline__ float lo16f(unsigned v) {
    union { float f; unsigned i; } c; c.i = v << 16; return c.f;
}
__device__ __forceinline__ float hi16f(unsigned v) {
    union { float f; unsigned i; } c; c.i = v & 0xffff0000u; return c.f;
}
// async global->LDS, 16B per lane; LDS dest = wave-uniform base + lane*16
__device__ __forceinline__ void gload16(const unsigned short* g, unsigned short* l) {
    __builtin_amdgcn_global_load_lds(
        (const __attribute__((address_space(1))) void*)g,
        (__attribute__((address_space(3))) void*)l, 16, 0, 0);
}

// ---------------------------------------------------------------- weight f32->bf16
__global__ __launch_bounds__(256) void wcvt_k(const float* __restrict__ w,
                                              unsigned short* __restrict__ o, int n4) {
    int i = blockIdx.x * 256 + threadIdx.x;
    if (i >= n4) return;
    float4 v = ((const float4*)w)[i];
    ushort4 u = make_ushort4(f2b(v.x), f2b(v.y), f2b(v.z), f2b(v.w));
    ((ushort4*)o)[i] = u;
}

// ---------------------------------------------------------------- dw weight transpose + bn2 fold
__global__ __launch_bounds__(256) void wprep_k(const float* __restrict__ wdw,
    const float* __restrict__ g, const float* __restrict__ bt,
    const float* __restrict__ mu, const float* __restrict__ va,
    float* __restrict__ wt, float* __restrict__ scf, float* __restrict__ shf) {
    int ch = blockIdx.x * 256 + threadIdx.x;   // 1024 total
    #pragma unroll
    for (int tap = 0; tap < 9; ++tap)
        wt[tap * 1024 + ch] = wdw[ch * 9 + tap];
    float s = g[ch] * rsqrtf(va[ch] + EPSV);
    scf[ch] = s;
    shf[ch] = bt[ch] - mu[ch] * s;
}

// ---------------------------------------------------------------- bn0+gelu + NCHW->NHWC
__global__ __launch_bounds__(256) void bn0tr_k(const float* __restrict__ x,
    const float* __restrict__ g, const float* __restrict__ bt,
    const float* __restrict__ mu, const float* __restrict__ va,
    unsigned short* __restrict__ h0b, float* __restrict__ xt) {
    __shared__ float tile[64][65];
    int hw0 = blockIdx.x * 64, c0 = blockIdx.y * 64, b = blockIdx.z;
    int t = threadIdx.x;
    int cl = t >> 6, hl = t & 63;
    #pragma unroll
    for (int r = 0; r < 16; ++r)
        tile[r * 4 + cl][hl] = x[((size_t)(b * 256 + c0 + r * 4 + cl)) * 1024 + hw0 + hl];
    __syncthreads();
    int c = c0 + (t & 63);
    float s = g[c] * rsqrtf(va[c] + EPSV);
    float m_ = mu[c], be = bt[c];
    #pragma unroll
    for (int r = 0; r < 16; ++r) {
        int hl2 = r * 4 + (t >> 6);
        float v = tile[t & 63][hl2];
        size_t o = ((size_t)(b * 1024 + hw0 + hl2)) * 256 + c;
        xt[o] = v;
        h0b[o] = f2b(gelu_f((v - m_) * s + be));
    }
}

// ---------------------------------------------------------------- per-window mean of gelu(bn0(x)), f32 (exact)
__global__ __launch_bounds__(256) void hm_k(const float* __restrict__ xt,
    const float* __restrict__ g, const float* __restrict__ bt,
    const float* __restrict__ mu, const float* __restrict__ va,
    float* __restrict__ hm) {
    int blk = blockIdx.x;           // b*64 + win
    int b = blk >> 6, win = blk & 63;
    int c = threadIdx.x;
    int base = (win >> 3) * 128 + (win & 7) * 4;
    float s = g[c] * rsqrtf(va[c] + EPSV);
    float m_ = mu[c], be = bt[c];
    float acc = 0.f;
    #pragma unroll
    for (int ty = 0; ty < 4; ++ty)
        #pragma unroll
        for (int tx = 0; tx < 4; ++tx) {
            float v = xt[((size_t)(b * 1024 + base + ty * 32 + tx)) * 256 + c];
            acc += gelu_f((v - m_) * s + be);
        }
    hm[(size_t)blk * 256 + c] = acc * (1.f / 16.f);
}

// ---------------------------------------------------------------- MFMA GEMM, 128x128 tile, BK=32
template <int MODE>
__global__ __launch_bounds__(256) void mgemm(
    const unsigned short* __restrict__ A, const unsigned short* __restrict__ X,
    unsigned short* __restrict__ outb, float* __restrict__ outf,
    const float* __restrict__ res,
    const float* __restrict__ p0, const float* __restrict__ p1,
    const float* __restrict__ p2, const float* __restrict__ p3,
    int M, int Kd) {
    __shared__ __align__(16) unsigned short As[4096];   // [128 m][32 k]
    __shared__ __align__(16) unsigned short Bs[4096];   // [128 n][32 k]
    const int t = threadIdx.x;
    const int wid = t >> 6, lane = t & 63;
    const int n0 = blockIdx.x * 128, m0 = blockIdx.y * 128, b = blockIdx.z;
    const unsigned short* Ab = A + (size_t)m0 * Kd;
    const unsigned short* Xb = X + ((size_t)b * 1024 + n0) * Kd;

    const int srow = lane >> 2;
    const int skb  = (lane & 3) * 8;
    const int wr = wid >> 1, wc = wid & 1;
    const int lr = lane & 15;
    const int lk = (lane >> 4) * 8;

    f32x4 acc[4][4] = {};

    for (int k0 = 0; k0 < Kd; k0 += 32) {
        #pragma unroll
        for (int i = 0; i < 2; ++i) {
            int chunk = wid * 2 + i;
            int row = chunk * 16 + srow;
            gload16(Ab + (size_t)row * Kd + k0 + skb, &As[chunk * 512]);
            gload16(Xb + (size_t)row * Kd + k0 + skb, &Bs[chunk * 512]);
        }
        __syncthreads();
        bf16x8 af[4], bfv[4];
        #pragma unroll
        for (int mi = 0; mi < 4; ++mi)
            af[mi] = *(const bf16x8*)&As[(wr * 64 + mi * 16 + lr) * 32 + lk];
        #pragma unroll
        for (int ni = 0; ni < 4; ++ni)
            bfv[ni] = *(const bf16x8*)&Bs[(wc * 64 + ni * 16 + lr) * 32 + lk];
        #pragma unroll
        for (int mi = 0; mi < 4; ++mi)
            #pragma unroll
            for (int ni = 0; ni < 4; ++ni)
                acc[mi][ni] = __builtin_amdgcn_mfma_f32_16x16x32_bf16(
                    af[mi], bfv[ni], acc[mi][ni], 0, 0, 0);
        __syncthreads();
    }

    const int crow = (lane >> 4) * 4;
    #pragma unroll
    for (int ni = 0; ni < 4; ++ni) {
        const int n = n0 + wc * 64 + ni * 16 + lr;
        #pragma unroll
        for (int mi = 0; mi < 4; ++mi) {
            const int m = m0 + wr * 64 + mi * 16 + crow;
            f32x4 v = acc[mi][ni];
            size_t o = ((size_t)b * 1024 + n) * (size_t)M + m;
            if (MODE == 0) {
                *(ushort4*)(outb + o) = make_ushort4(f2b(v[0]), f2b(v[1]), f2b(v[2]), f2b(v[3]));
            } else if (MODE == 1) {
                float4 r = *(const float4*)(res + o);
                float4 bi = *(const float4*)(p0 + m);
                float w0 = v[0] + r.x + bi.x, w1 = v[1] + r.y + bi.y;
                float w2 = v[2] + r.z + bi.z, w3 = v[3] + r.w + bi.w;
                *(float4*)(outf + o) = make_float4(w0, w1, w2, w3);
                *(ushort4*)(outb + o) = make_ushort4(f2b(w0), f2b(w1), f2b(w2), f2b(w3));
            } else if (MODE == 2) {
                float4 gg = *(const float4*)(p0 + m);
                float4 be = *(const float4*)(p1 + m);
                float4 mm = *(const float4*)(p2 + m);
                float4 vv = *(const float4*)(p3 + m);
                float h0 = gelu_f((v[0] - mm.x) * (gg.x * rsqrtf(vv.x + EPSV)) + be.x);
                float h1 = gelu_f((v[1] - mm.y) * (gg.y * rsqrtf(vv.y + EPSV)) + be.y);
                float h2 = gelu_f((v[2] - mm.z) * (gg.z * rsqrtf(vv.z + EPSV)) + be.z);
                float h3 = gelu_f((v[3] - mm.w) * (gg.w * rsqrtf(vv.w + EPSV)) + be.w);
                *(ushort4*)(outb + o) = make_ushort4(f2b(h0), f2b(h1), f2b(h2), f2b(h3));
            } else {
                float4 gg = *(const float4*)(p0 + m);
                float4 be = *(const float4*)(p1 + m);
                float4 mm = *(const float4*)(p2 + m);
                float4 vv = *(const float4*)(p3 + m);
                float4 r = *(const float4*)(res + o);
                float y0 = (v[0] - mm.x) * (gg.x * rsqrtf(vv.x + EPSV)) + be.x + r.x;
                float y1 = (v[1] - mm.y) * (gg.y * rsqrtf(vv.y + EPSV)) + be.y + r.y;
                float y2 = (v[2] - mm.z) * (gg.z * rsqrtf(vv.z + EPSV)) + be.z + r.z;
                float y3 = (v[3] - mm.w) * (gg.w * rsqrtf(vv.w + EPSV)) + be.w + r.w;
                *(float4*)(outf + o) = make_float4(y0, y1, y2, y3);
            }
        }
    }
}

// ---------------------------------------------------------------- descriptor GEMM (f32 exact, tiled)
__global__ __launch_bounds__(256) void desc2_k(const float* __restrict__ hm,
                                               const float* __restrict__ w_qkv,
                                               float* __restrict__ qkd) {
    __shared__ float As[16][64];   // [k][o]
    __shared__ float Bs[16][64];   // [k][row]
    float acc[4][4] = {{0.f}};
    const int t = threadIdx.x;
    const int tn = t & 15, tm = t >> 4;
    const int n0 = blockIdx.x * 64;   // row tile
    const int m0 = blockIdx.y * 64;   // output tile
    for (int k0 = 0; k0 < 256; k0 += 16) {
        {
            int r  = t >> 2;
            int k4 = (t & 3) << 2;
            float4 a4 = *(const float4*)(w_qkv + (size_t)(m0 + r) * 256 + k0 + k4);
            As[k4 + 0][r] = a4.x; As[k4 + 1][r] = a4.y;
            As[k4 + 2][r] = a4.z; As[k4 + 3][r] = a4.w;
            float4 b4 = *(const float4*)(hm + (size_t)(n0 + r) * 256 + k0 + k4);
            Bs[k4 + 0][r] = b4.x; Bs[k4 + 1][r] = b4.y;
            Bs[k4 + 2][r] = b4.z; Bs[k4 + 3][r] = b4.w;
        }
        __syncthreads();
        #pragma unroll
        for (int kk = 0; kk < 16; ++kk) {
            float4 av = *(const float4*)&As[kk][tm << 2];
            float4 bv = *(const float4*)&Bs[kk][tn << 2];
            float a0[4] = {av.x, av.y, av.z, av.w};
            float b0[4] = {bv.x, bv.y, bv.z, bv.w};
            #pragma unroll
            for (int i = 0; i < 4; ++i)
                #pragma unroll
                for (int j = 0; j < 4; ++j)
                    acc[i][j] += a0[i] * b0[j];
        }
        __syncthreads();
    }
    #pragma unroll
    for (int j = 0; j < 4; ++j) {
        int row = n0 + (tn << 2) + j;
        float4 v = make_float4(acc[0][j], acc[1][j], acc[2][j], acc[3][j]);
        *(float4*)(qkd + (size_t)row * 512 + m0 + (tm << 2)) = v;
    }
}

// ---------------------------------------------------------------- affinity + top-4 per (b,h)
__global__ __launch_bounds__(256) void aff_k(const float* __restrict__ qkd,
                                             int* __restrict__ idx_out) {
    int bh = blockIdx.x;            // b*8 + h (128)
    int b = bh >> 3, h = bh & 7;
    __shared__ float qdl[64][33];
    __shared__ float kdl[64][33];
    __shared__ float wsc[64][65];
    int t = threadIdx.x;
    for (int e = t; e < 2048; e += 256) {
        int wn = e >> 5, d = e & 31;
        size_t src = ((size_t)(b * 64 + wn)) * 512 + h * 32 + d;
        qdl[wn][d] = qkd[src];
        kdl[wn][d] = qkd[src + 256];
    }
    __syncthreads();
    {
        int i = t >> 2, j0 = (t & 3) * 16;
        float s[16];
        #pragma unroll
        for (int j = 0; j < 16; ++j) s[j] = 0.f;
        #pragma unroll
        for (int d = 0; d < 32; ++d) {
            float qv = qdl[i][d];
            #pragma unroll
            for (int j = 0; j < 16; ++j) s[j] += qv * kdl[j0 + j][d];
        }
        #pragma unroll
        for (int j = 0; j < 16; ++j) wsc[i][j0 + j] = s[j];
    }
    __syncthreads();
    if (t < 64) {
        float bv[4] = {-1e30f, -1e30f, -1e30f, -1e30f};
        int   bi[4] = {0, 0, 0, 0};
        for (int j = 0; j < 64; ++j) {
            float v = wsc[t][j];
            if (v > bv[3]) {
                int p = 3;
                while (p > 0 && v > bv[p - 1]) {
                    bv[p] = bv[p - 1]; bi[p] = bi[p - 1]; --p;
                }
                bv[p] = v; bi[p] = j;
            }
        }
        int* o = idx_out + (bh * 64 + t) * 4;
        o[0] = bi[0]; o[1] = bi[1]; o[2] = bi[2]; o[3] = bi[3];
    }
}

// ---------------------------------------------------------------- gathered window attention, MFMA
// One wave per window; 4 windows per block. Q/K/V staged bf16 in padded LDS;
// QK^T = 4 MFMA, softmax in-register (16-lane shfl groups), PV = 4 MFMA.
// Fragment indexing mirrors mgemm (numerically verified).
__global__ __launch_bounds__(256) void attn_k(const unsigned short* __restrict__ qkv,
                                              const int* __restrict__ idx,
                                              unsigned short* __restrict__ msg) {
    __shared__ __align__(16) unsigned short qs[4][16][40];   // [tok][d], +8 pad
    __shared__ __align__(16) unsigned short ks[4][64][40];   // [key][d], +8 pad
    __shared__ __align__(16) unsigned short vt[4][32][72];   // [d][key], +8 pad
    __shared__ __align__(16) unsigned short ps[4][16][72];   // [tok][key], +8 pad
    const int t = threadIdx.x;
    const int wid = t >> 6, lane = t & 63;
    const int g = blockIdx.x * 4 + wid;        // global window id
    const int win = g & 63;
    const int bh = g >> 6;
    const int b = bh >> 3, h = bh & 7;
    const int qb = (win >> 3) * 128 + (win & 7) * 4;
    const int* widx = idx + (bh * 64 + win) * 4;

    // gather Q (16 tok x 32 d): uint2 = 4 bf16, stored raw
    for (int e = lane; e < 128; e += 64) {
        int tok = e >> 3, d4 = (e & 7) * 4;
        int hw = qb + (tok >> 2) * 32 + (tok & 3);
        uint2 u = *(const uint2*)&qkv[((size_t)(b * 1024 + hw)) * 768 + h * 32 + d4];
        *(uint2*)&qs[wid][tok][d4] = u;
    }
    // gather K (row-major) + V (transposed)
    for (int e = lane; e < 512; e += 64) {
        int key = e >> 3, d4 = (e & 7) * 4;
        int wsel = widx[key >> 4];
        int tok = key & 15;
        int hw = (wsel >> 3) * 128 + (wsel & 7) * 4 + (tok >> 2) * 32 + (tok & 3);
        size_t base = ((size_t)(b * 1024 + hw)) * 768 + h * 32 + d4;
        uint2 uk = *(const uint2*)&qkv[base + 256];
        uint2 uv = *(const uint2*)&qkv[base + 512];
        *(uint2*)&ks[wid][key][d4] = uk;
        vt[wid][d4 + 0][key] = (unsigned short)(uv.x & 0xffffu);
        vt[wid][d4 + 1][key] = (unsigned short)(uv.x >> 16);
        vt[wid][d4 + 2][key] = (unsigned short)(uv.y & 0xffffu);
        vt[wid][d4 + 3][key] = (unsigned short)(uv.y >> 16);
    }
    __syncthreads();

    const int lr = lane & 15;
    const int lk8 = (lane >> 4) * 8;
    const float scale = 0.17677669529663688f;   // 1/sqrt(32)
    f32x4 zero = {0.f, 0.f, 0.f, 0.f};

    // QK^T: S[16 q][64 key] = Q(A) x K^T(B), 4 n-tiles
    bf16x8 qA = *(const bf16x8*)&qs[wid][lr][lk8];
    f32x4 sa[4];
    #pragma unroll
    for (int kt = 0; kt < 4; ++kt) {
        bf16x8 kB = *(const bf16x8*)&ks[wid][kt * 16 + lr][lk8];
        sa[kt] = __builtin_amdgcn_mfma_f32_16x16x32_bf16(qA, kB, zero, 0, 0, 0);
    }
    // softmax per q-row (row = (lane>>4)*4+i; key cols split lane&15 x kt)
    #pragma unroll
    for (int i = 0; i < 4; ++i) {
        float s0 = sa[0][i] * scale, s1 = sa[1][i] * scale;
        float s2 = sa[2][i] * scale, s3 = sa[3][i] * scale;
        float mx = fmaxf(fmaxf(s0, s1), fmaxf(s2, s3));
        #pragma unroll
        for (int m = 1; m < 16; m <<= 1) mx = fmaxf(mx, __shfl_xor(mx, m));
        float e0 = expf(s0 - mx), e1 = expf(s1 - mx);
        float e2 = expf(s2 - mx), e3 = expf(s3 - mx);
        float sm = e0 + e1 + e2 + e3;
        #pragma unroll
        for (int m = 1; m < 16; m <<= 1) sm += __shfl_xor(sm, m);
        float inv = 1.0f / sm;
        int row = (lane >> 4) * 4 + i;
        ps[wid][row][ 0 + lr] = f2b(e0 * inv);
        ps[wid][row][16 + lr] = f2b(e1 * inv);
        ps[wid][row][32 + lr] = f2b(e2 * inv);
        ps[wid][row][48 + lr] = f2b(e3 * inv);
    }
    __syncthreads();
    // PV: O[16 q][32 d] = P(A, K=64) x V(B via vt), 2 n-tiles x 2 k-halves
    f32x4 oa[2] = {zero, zero};
    #pragma unroll
    for (int kh = 0; kh < 2; ++kh) {
        bf16x8 pA = *(const bf16x8*)&ps[wid][lr][kh * 32 + lk8];
        #pragma unroll
        for (int nt = 0; nt < 2; ++nt) {
            bf16x8 vB = *(const bf16x8*)&vt[wid][nt * 16 + lr][kh * 32 + lk8];
            oa[nt] = __builtin_amdgcn_mfma_f32_16x16x32_bf16(pA, vB, oa[nt], 0, 0, 0);
        }
    }
    // store O (C-layout: col d = nt*16+lr, row tok = (lane>>4)*4+i)
    #pragma unroll
    for (int nt = 0; nt < 2; ++nt) {
        int d = nt * 16 + lr;
        #pragma unroll
        for (int i = 0; i < 4; ++i) {
            int tok = (lane >> 4) * 4 + i;
            int hw = qb + (tok >> 2) * 32 + (tok & 3);
            msg[((size_t)(b * 1024 + hw)) * 256 + h * 32 + d] = f2b(oa[nt][i]);
        }
    }
}

// ---------------------------------------------------------------- K5: depthwise 3x3 + bn2 + gelu, vectorized
__global__ __launch_bounds__(256) void dw_k(const unsigned short* __restrict__ h1,
    const float* __restrict__ wt, const float* __restrict__ scf,
    const float* __restrict__ shf, unsigned short* __restrict__ h2) {
    int t = threadIdx.x;
    int c8 = t & 127;             // channel octet 0..127
    int pl = t >> 7;              // 0/1
    int blk = blockIdx.x;         // 2048 total: b(16) * y(32) * xg(4)
    int b = blk >> 7;
    int rem = blk & 127;
    int y = rem >> 2;
    int x0 = (rem & 3) * 8;
    int ch0 = c8 * 8;

    float w[9][8];
    #pragma unroll
    for (int tap = 0; tap < 9; ++tap) {
        float4 a = *(const float4*)(wt + tap * 1024 + ch0);
        float4 bq = *(const float4*)(wt + tap * 1024 + ch0 + 4);
        w[tap][0] = a.x; w[tap][1] = a.y; w[tap][2] = a.z; w[tap][3] = a.w;
        w[tap][4] = bq.x; w[tap][5] = bq.y; w[tap][6] = bq.z; w[tap][7] = bq.w;
    }
    float sc[8], sh[8];
    {
        float4 a = *(const float4*)(scf + ch0);
        float4 bq = *(const float4*)(scf + ch0 + 4);
        sc[0]=a.x; sc[1]=a.y; sc[2]=a.z; sc[3]=a.w; sc[4]=bq.x; sc[5]=bq.y; sc[6]=bq.z; sc[7]=bq.w;
        float4 c = *(const float4*)(shf + ch0);
        float4 dq = *(const float4*)(shf + ch0 + 4);
        sh[0]=c.x; sh[1]=c.y; sh[2]=c.z; sh[3]=c.w; sh[4]=dq.x; sh[5]=dq.y; sh[6]=dq.z; sh[7]=dq.w;
    }

    const unsigned short* base = h1 + (size_t)b * 1048576;
    unsigned short* ob = h2 + (size_t)b * 1048576;

    #pragma unroll
    for (int j = 0; j < 4; ++j) {
        int x = x0 + pl + 2 * j;
        float acc[8] = {0.f,0.f,0.f,0.f,0.f,0.f,0.f,0.f};
        #pragma unroll
        for (int dy = -1; dy <= 1; ++dy) {
            int yy = y + dy;
            if (yy < 0 || yy > 31) continue;
            #pragma unroll
            for (int dx = -1; dx <= 1; ++dx) {
                int xx = x + dx;
                if (xx < 0 || xx > 31) continue;
                uint4 u = *(const uint4*)(base + (size_t)(yy * 32 + xx) * 1024 + ch0);
                int tap = (dy + 1) * 3 + (dx + 1);
                acc[0] += lo16f(u.x) * w[tap][0];
                acc[1] += hi16f(u.x) * w[tap][1];
                acc[2] += lo16f(u.y) * w[tap][2];
                acc[3] += hi16f(u.y) * w[tap][3];
                acc[4] += lo16f(u.z) * w[tap][4];
                acc[5] += hi16f(u.z) * w[tap][5];
                acc[6] += lo16f(u.w) * w[tap][6];
                acc[7] += hi16f(u.w) * w[tap][7];
            }
        }
        unsigned short r[8];
        #pragma unroll
        for (int c = 0; c < 8; ++c)
            r[c] = f2b(gelu_f(acc[c] * sc[c] + sh[c]));
        uint4 o;
        o.x = (unsigned)r[0] | ((unsigned)r[1] << 16);
        o.y = (unsigned)r[2] | ((unsigned)r[3] << 16);
        o.z = (unsigned)r[4] | ((unsigned)r[5] << 16);
        o.w = (unsigned)r[6] | ((unsigned)r[7] << 16);
        *(uint4*)(ob + (size_t)(y * 32 + x) * 1024 + ch0) = o;
    }
}

// ---------------------------------------------------------------- NHWC f32 -> NCHW f32 (final)
__global__ __launch_bounds__(256) void trout_k(const float* __restrict__ y,
                                               float* __restrict__ out) {
    __shared__ float tile[64][65];
    int hw0 = blockIdx.x * 64, c0 = blockIdx.y * 64, b = blockIdx.z;
    int t = threadIdx.x;
    #pragma unroll
    for (int r = 0; r < 16; ++r) {
        int hl = r * 4 + (t >> 6);
        tile[t & 63][hl] = y[((size_t)(b * 1024 + hw0 + hl)) * 256 + c0 + (t & 63)];
    }
    __syncthreads();
    #pragma unroll
    for (int r = 0; r < 16; ++r) {
        int cl = r * 4 + (t >> 6);
        out[((size_t)(b * 256 + c0 + cl)) * 1024 + hw0 + (t & 63)] = tile[cl][t & 63];
    }
}

// ---------------------------------------------------------------- launch
extern "C" void kernel_launch(void* const* d_in, const int* in_sizes, int n_in,
                              void* d_out, int out_size, void* d_ws, size_t ws_size,
                              hipStream_t stream) {
    const float* x      = (const float*)d_in[0];
    const float* bn0_g  = (const float*)d_in[1];
    const float* bn0_b  = (const float*)d_in[2];
    const float* bn0_m  = (const float*)d_in[3];
    const float* bn0_v  = (const float*)d_in[4];
    const float* w_qkv  = (const float*)d_in[5];
    const float* w_merge= (const float*)d_in[6];
    const float* b_merge= (const float*)d_in[7];
    const float* w1     = (const float*)d_in[8];
    const float* bn1_g  = (const float*)d_in[9];
    const float* bn1_b  = (const float*)d_in[10];
    const float* bn1_m  = (const float*)d_in[11];
    const float* bn1_v  = (const float*)d_in[12];
    const float* dw     = (const float*)d_in[13];
    const float* bn2_g  = (const float*)d_in[14];
    const float* bn2_b  = (const float*)d_in[15];
    const float* bn2_m  = (const float*)d_in[16];
    const float* bn2_v  = (const float*)d_in[17];
    const float* w2     = (const float*)d_in[18];
    const float* bn3_g  = (const float*)d_in[19];
    const float* bn3_b  = (const float*)d_in[20];
    const float* bn3_m  = (const float*)d_in[21];
    const float* bn3_v  = (const float*)d_in[22];
    float* out = (float*)d_out;

    char* w = (char*)d_ws;
    unsigned short* h0b   = (unsigned short*)(w);                // [b][hw][256] bf16
    unsigned short* qkvb  = (unsigned short*)(w + 8388608);      // [b][hw][768] bf16
    unsigned short* msgb  = (unsigned short*)(w + 33554432);     // [b][hw][256] bf16
    unsigned short* xrb   = (unsigned short*)(w + 41943040);     // [b][hw][256] bf16
    unsigned short* h1b   = (unsigned short*)(w + 50331648);     // [b][hw][1024] bf16
    unsigned short* h2b   = (unsigned short*)(w + 83886080);     // [b][hw][1024] bf16
    float*  xt    = (float*)(w + 117440512);                     // [b][hw][256] f32 (raw x)
    float*  xrf   = (float*)(w + 134217728);                     // [b][hw][256] f32
    float*  yf    = (float*)(w + 150994944);                     // [b][hw][256] f32
    float*  hm    = (float*)(w + 167772160);                     // [b][64][256] f32
    unsigned short* wqkvb = (unsigned short*)(w + 168820736);
    unsigned short* wmrgb = (unsigned short*)(w + 169213952);
    unsigned short* w1b   = (unsigned short*)(w + 169345024);
    unsigned short* w2b   = (unsigned short*)(w + 169869312);
    int*    idx   = (int*)(w + 170393600);                       // 131072 B
    float*  wtbuf = (float*)(w + 170524672);                     // 9*1024 f32
    float*  scbuf = (float*)(w + 170561536);                     // 1024 f32
    float*  shbuf = (float*)(w + 170565632);                     // 1024 f32
    float*  qkdbuf= (float*)(w + 170569728);                     // [1024][512] f32 (2 MB)

    // weights -> bf16 + dw prep
    wcvt_k<<<192, 256, 0, stream>>>(w_qkv, wqkvb, 49152);
    wcvt_k<<<64,  256, 0, stream>>>(w_merge, wmrgb, 16384);
    wcvt_k<<<256, 256, 0, stream>>>(w1, w1b, 65536);
    wcvt_k<<<256, 256, 0, stream>>>(w2, w2b, 65536);
    wprep_k<<<4, 256, 0, stream>>>(dw, bn2_g, bn2_b, bn2_m, bn2_v, wtbuf, scbuf, shbuf);

    // bn0+gelu + transpose to NHWC
    bn0tr_k<<<dim3(16, 4, 16), 256, 0, stream>>>(x, bn0_g, bn0_b, bn0_m, bn0_v, h0b, xt);
    // exact f32 window means
    hm_k<<<1024, 256, 0, stream>>>(xt, bn0_g, bn0_b, bn0_m, bn0_v, hm);
    // qkv = w_qkv @ h0
    mgemm<0><<<dim3(8, 6, 16), 256, 0, stream>>>(wqkvb, h0b, qkvb, nullptr,
        nullptr, nullptr, nullptr, nullptr, nullptr, 768, 256);
    // descriptors (tiled f32 GEMM) + top-k
    desc2_k<<<dim3(16, 8), 256, 0, stream>>>(hm, w_qkv, qkdbuf);
    aff_k<<<128, 256, 0, stream>>>(qkdbuf, idx);
    // attention (MFMA, 4 windows/block)
    attn_k<<<2048, 256, 0, stream>>>(qkvb, idx, msgb);
    // xr = x + w_merge@msg + bias
    mgemm<1><<<dim3(8, 2, 16), 256, 0, stream>>>(wmrgb, msgb, xrb, xrf,
        xt, b_merge, nullptr, nullptr, nullptr, 256, 256);
    // h1 = gelu(bn1(w1@xr))
    mgemm<2><<<dim3(8, 8, 16), 256, 0, stream>>>(w1b, xrb, h1b, nullptr,
        nullptr, bn1_g, bn1_b, bn1_m, bn1_v, 1024, 256);
    // h2 = gelu(bn2(dw3x3(h1)))  — vectorized
    dw_k<<<2048, 256, 0, stream>>>(h1b, wtbuf, scbuf, shbuf, h2b);
    // y = bn3(w2@h2) + xr  (f32 NHWC)
    mgemm<3><<<dim3(8, 2, 16), 256, 0, stream>>>(w2b, h2b, nullptr, yf,
        xrf, bn3_g, bn3_b, bn3_m, bn3_v, 256, 1024);
    // NHWC -> NCHW
    trout_k<<<dim3(16, 4, 16), 256, 0, stream>>>(yf, out);
}

// Round 14
// 329.200 us; speedup vs baseline: 1.3640x; 1.0486x over previous
//
#include <hip/hip_runtime.h>
#include <hip/hip_bf16.h>

#define EPSV 1e-5f

typedef short bf16x8 __attribute__((ext_vector_type(8)));
typedef float f32x4 __attribute__((ext_vector_type(4)));

__device__ __forceinline__ float gelu_f(float x) {
    return 0.5f * x * (1.0f + erff(x * 0.70710678118654752f));
}
__device__ __forceinline__ float b2f(unsigned short u) {
    union { float f; unsigned i; } c; c.i = ((unsigned)u) << 16; return c.f;
}
__device__ __forceinline__ unsigned short f2b(float f) {
    __hip_bfloat16 h = __float2bfloat16(f);
    return *reinterpret_cast<unsigned short*>(&h);
}
__device__ __forceinline__ float lo16f(unsigned v) {
    union { float f; unsigned i; } c; c.i = v << 16; return c.f;
}
__device__ __forceinline__ float hi16f(unsigned v) {
    union { float f; unsigned i; } c; c.i = v & 0xffff0000u; return c.f;
}
// async global->LDS, 16B per lane; LDS dest = wave-uniform base + lane*16
__device__ __forceinline__ void gload16(const unsigned short* g, unsigned short* l) {
    __builtin_amdgcn_global_load_lds(
        (const __attribute__((address_space(1))) void*)g,
        (__attribute__((address_space(3))) void*)l, 16, 0, 0);
}

// ---------------------------------------------------------------- all weights f32->bf16 (one launch)
__global__ __launch_bounds__(256) void wcvt4_k(
    const float* __restrict__ wqkv, const float* __restrict__ wm,
    const float* __restrict__ w1, const float* __restrict__ w2,
    unsigned short* __restrict__ oq, unsigned short* __restrict__ om,
    unsigned short* __restrict__ o1, unsigned short* __restrict__ o2) {
    int i = blockIdx.x * 256 + threadIdx.x;        // 196608 float4s total
    const float* src; unsigned short* dst; int off;
    if (i < 49152)       { src = wqkv; dst = oq; off = i; }
    else if (i < 65536)  { src = wm;   dst = om; off = i - 49152; }
    else if (i < 131072) { src = w1;   dst = o1; off = i - 65536; }
    else                 { src = w2;   dst = o2; off = i - 131072; }
    float4 v = ((const float4*)src)[off];
    ((ushort4*)dst)[off] = make_ushort4(f2b(v.x), f2b(v.y), f2b(v.z), f2b(v.w));
}

// ---------------------------------------------------------------- dw weight transpose + bn2 fold
__global__ __launch_bounds__(256) void wprep_k(const float* __restrict__ wdw,
    const float* __restrict__ g, const float* __restrict__ bt,
    const float* __restrict__ mu, const float* __restrict__ va,
    float* __restrict__ wt, float* __restrict__ scf, float* __restrict__ shf) {
    int ch = blockIdx.x * 256 + threadIdx.x;   // 1024 total
    #pragma unroll
    for (int tap = 0; tap < 9; ++tap)
        wt[tap * 1024 + ch] = wdw[ch * 9 + tap];
    float s = g[ch] * rsqrtf(va[ch] + EPSV);
    scf[ch] = s;
    shf[ch] = bt[ch] - mu[ch] * s;
}

// ---------------------------------------------------------------- bn0+gelu + NCHW->NHWC
__global__ __launch_bounds__(256) void bn0tr_k(const float* __restrict__ x,
    const float* __restrict__ g, const float* __restrict__ bt,
    const float* __restrict__ mu, const float* __restrict__ va,
    unsigned short* __restrict__ h0b, float* __restrict__ xt) {
    __shared__ float tile[64][65];
    int hw0 = blockIdx.x * 64, c0 = blockIdx.y * 64, b = blockIdx.z;
    int t = threadIdx.x;
    int cl = t >> 6, hl = t & 63;
    #pragma unroll
    for (int r = 0; r < 16; ++r)
        tile[r * 4 + cl][hl] = x[((size_t)(b * 256 + c0 + r * 4 + cl)) * 1024 + hw0 + hl];
    __syncthreads();
    int c = c0 + (t & 63);
    float s = g[c] * rsqrtf(va[c] + EPSV);
    float m_ = mu[c], be = bt[c];
    #pragma unroll
    for (int r = 0; r < 16; ++r) {
        int hl2 = r * 4 + (t >> 6);
        float v = tile[t & 63][hl2];
        size_t o = ((size_t)(b * 1024 + hw0 + hl2)) * 256 + c;
        xt[o] = v;
        h0b[o] = f2b(gelu_f((v - m_) * s + be));
    }
}

// ---------------------------------------------------------------- per-window mean of gelu(bn0(x)), f32 (exact)
__global__ __launch_bounds__(256) void hm_k(const float* __restrict__ xt,
    const float* __restrict__ g, const float* __restrict__ bt,
    const float* __restrict__ mu, const float* __restrict__ va,
    float* __restrict__ hm) {
    int blk = blockIdx.x;           // b*64 + win
    int b = blk >> 6, win = blk & 63;
    int c = threadIdx.x;
    int base = (win >> 3) * 128 + (win & 7) * 4;
    float s = g[c] * rsqrtf(va[c] + EPSV);
    float m_ = mu[c], be = bt[c];
    float acc = 0.f;
    #pragma unroll
    for (int ty = 0; ty < 4; ++ty)
        #pragma unroll
        for (int tx = 0; tx < 4; ++tx) {
            float v = xt[((size_t)(b * 1024 + base + ty * 32 + tx)) * 256 + c];
            acc += gelu_f((v - m_) * s + be);
        }
    hm[(size_t)blk * 256 + c] = acc * (1.f / 16.f);
}

// ---------------------------------------------------------------- MFMA GEMM, 128x128 tile, BK=32
// MODE 3 writes the FINAL NCHW f32 output directly (trout fused).
template <int MODE>
__global__ __launch_bounds__(256) void mgemm(
    const unsigned short* __restrict__ A, const unsigned short* __restrict__ X,
    unsigned short* __restrict__ outb, float* __restrict__ outf,
    const float* __restrict__ res,
    const float* __restrict__ p0, const float* __restrict__ p1,
    const float* __restrict__ p2, const float* __restrict__ p3,
    int M, int Kd) {
    __shared__ __align__(16) unsigned short As[4096];   // [128 m][32 k]
    __shared__ __align__(16) unsigned short Bs[4096];   // [128 n][32 k]
    const int t = threadIdx.x;
    const int wid = t >> 6, lane = t & 63;
    const int n0 = blockIdx.x * 128, m0 = blockIdx.y * 128, b = blockIdx.z;
    const unsigned short* Ab = A + (size_t)m0 * Kd;
    const unsigned short* Xb = X + ((size_t)b * 1024 + n0) * Kd;

    const int srow = lane >> 2;
    const int skb  = (lane & 3) * 8;
    const int wr = wid >> 1, wc = wid & 1;
    const int lr = lane & 15;
    const int lk = (lane >> 4) * 8;

    f32x4 acc[4][4] = {};

    for (int k0 = 0; k0 < Kd; k0 += 32) {
        #pragma unroll
        for (int i = 0; i < 2; ++i) {
            int chunk = wid * 2 + i;
            int row = chunk * 16 + srow;
            gload16(Ab + (size_t)row * Kd + k0 + skb, &As[chunk * 512]);
            gload16(Xb + (size_t)row * Kd + k0 + skb, &Bs[chunk * 512]);
        }
        __syncthreads();
        bf16x8 af[4], bfv[4];
        #pragma unroll
        for (int mi = 0; mi < 4; ++mi)
            af[mi] = *(const bf16x8*)&As[(wr * 64 + mi * 16 + lr) * 32 + lk];
        #pragma unroll
        for (int ni = 0; ni < 4; ++ni)
            bfv[ni] = *(const bf16x8*)&Bs[(wc * 64 + ni * 16 + lr) * 32 + lk];
        #pragma unroll
        for (int mi = 0; mi < 4; ++mi)
            #pragma unroll
            for (int ni = 0; ni < 4; ++ni)
                acc[mi][ni] = __builtin_amdgcn_mfma_f32_16x16x32_bf16(
                    af[mi], bfv[ni], acc[mi][ni], 0, 0, 0);
        __syncthreads();
    }

    const int crow = (lane >> 4) * 4;
    #pragma unroll
    for (int ni = 0; ni < 4; ++ni) {
        const int n = n0 + wc * 64 + ni * 16 + lr;
        #pragma unroll
        for (int mi = 0; mi < 4; ++mi) {
            const int m = m0 + wr * 64 + mi * 16 + crow;
            f32x4 v = acc[mi][ni];
            size_t o = ((size_t)b * 1024 + n) * (size_t)M + m;
            if (MODE == 0) {
                *(ushort4*)(outb + o) = make_ushort4(f2b(v[0]), f2b(v[1]), f2b(v[2]), f2b(v[3]));
            } else if (MODE == 1) {
                float4 r = *(const float4*)(res + o);
                float4 bi = *(const float4*)(p0 + m);
                float w0 = v[0] + r.x + bi.x, w1 = v[1] + r.y + bi.y;
                float w2 = v[2] + r.z + bi.z, w3 = v[3] + r.w + bi.w;
                *(float4*)(outf + o) = make_float4(w0, w1, w2, w3);
                *(ushort4*)(outb + o) = make_ushort4(f2b(w0), f2b(w1), f2b(w2), f2b(w3));
            } else if (MODE == 2) {
                float4 gg = *(const float4*)(p0 + m);
                float4 be = *(const float4*)(p1 + m);
                float4 mm = *(const float4*)(p2 + m);
                float4 vv = *(const float4*)(p3 + m);
                float h0 = gelu_f((v[0] - mm.x) * (gg.x * rsqrtf(vv.x + EPSV)) + be.x);
                float h1 = gelu_f((v[1] - mm.y) * (gg.y * rsqrtf(vv.y + EPSV)) + be.y);
                float h2 = gelu_f((v[2] - mm.z) * (gg.z * rsqrtf(vv.z + EPSV)) + be.z);
                float h3 = gelu_f((v[3] - mm.w) * (gg.w * rsqrtf(vv.w + EPSV)) + be.w);
                *(ushort4*)(outb + o) = make_ushort4(f2b(h0), f2b(h1), f2b(h2), f2b(h3));
            } else {
                // MODE 3: y = bn3(C) + res, stored directly NCHW (trout fused)
                float4 gg = *(const float4*)(p0 + m);
                float4 be = *(const float4*)(p1 + m);
                float4 mm = *(const float4*)(p2 + m);
                float4 vv = *(const float4*)(p3 + m);
                float4 r = *(const float4*)(res + o);
                float y0 = (v[0] - mm.x) * (gg.x * rsqrtf(vv.x + EPSV)) + be.x + r.x;
                float y1 = (v[1] - mm.y) * (gg.y * rsqrtf(vv.y + EPSV)) + be.y + r.y;
                float y2 = (v[2] - mm.z) * (gg.z * rsqrtf(vv.z + EPSV)) + be.z + r.z;
                float y3 = (v[3] - mm.w) * (gg.w * rsqrtf(vv.w + EPSV)) + be.w + r.w;
                size_t ob = ((size_t)b * 256 + m) * 1024 + n;   // [b][c=m][hw=n]
                outf[ob]          = y0;
                outf[ob + 1024]   = y1;
                outf[ob + 2048]   = y2;
                outf[ob + 3072]   = y3;
            }
        }
    }
}

// ---------------------------------------------------------------- descriptor GEMM (f32 exact, tiled)
__global__ __launch_bounds__(256) void desc2_k(const float* __restrict__ hm,
                                               const float* __restrict__ w_qkv,
                                               float* __restrict__ qkd) {
    __shared__ float As[16][64];   // [k][o]
    __shared__ float Bs[16][64];   // [k][row]
    float acc[4][4] = {{0.f}};
    const int t = threadIdx.x;
    const int tn = t & 15, tm = t >> 4;
    const int n0 = blockIdx.x * 64;   // row tile
    const int m0 = blockIdx.y * 64;   // output tile
    for (int k0 = 0; k0 < 256; k0 += 16) {
        {
            int r  = t >> 2;
            int k4 = (t & 3) << 2;
            float4 a4 = *(const float4*)(w_qkv + (size_t)(m0 + r) * 256 + k0 + k4);
            As[k4 + 0][r] = a4.x; As[k4 + 1][r] = a4.y;
            As[k4 + 2][r] = a4.z; As[k4 + 3][r] = a4.w;
            float4 b4 = *(const float4*)(hm + (size_t)(n0 + r) * 256 + k0 + k4);
            Bs[k4 + 0][r] = b4.x; Bs[k4 + 1][r] = b4.y;
            Bs[k4 + 2][r] = b4.z; Bs[k4 + 3][r] = b4.w;
        }
        __syncthreads();
        #pragma unroll
        for (int kk = 0; kk < 16; ++kk) {
            float4 av = *(const float4*)&As[kk][tm << 2];
            float4 bv = *(const float4*)&Bs[kk][tn << 2];
            float a0[4] = {av.x, av.y, av.z, av.w};
            float b0[4] = {bv.x, bv.y, bv.z, bv.w};
            #pragma unroll
            for (int i = 0; i < 4; ++i)
                #pragma unroll
                for (int j = 0; j < 4; ++j)
                    acc[i][j] += a0[i] * b0[j];
        }
        __syncthreads();
    }
    #pragma unroll
    for (int j = 0; j < 4; ++j) {
        int row = n0 + (tn << 2) + j;
        float4 v = make_float4(acc[0][j], acc[1][j], acc[2][j], acc[3][j]);
        *(float4*)(qkd + (size_t)row * 512 + m0 + (tm << 2)) = v;
    }
}

// ---------------------------------------------------------------- affinity + top-4 per (b,h)
__global__ __launch_bounds__(256) void aff_k(const float* __restrict__ qkd,
                                             int* __restrict__ idx_out) {
    int bh = blockIdx.x;            // b*8 + h (128)
    int b = bh >> 3, h = bh & 7;
    __shared__ float qdl[64][33];
    __shared__ float kdl[64][33];
    __shared__ float wsc[64][65];
    int t = threadIdx.x;
    for (int e = t; e < 2048; e += 256) {
        int wn = e >> 5, d = e & 31;
        size_t src = ((size_t)(b * 64 + wn)) * 512 + h * 32 + d;
        qdl[wn][d] = qkd[src];
        kdl[wn][d] = qkd[src + 256];
    }
    __syncthreads();
    {
        int i = t >> 2, j0 = (t & 3) * 16;
        float s[16];
        #pragma unroll
        for (int j = 0; j < 16; ++j) s[j] = 0.f;
        #pragma unroll
        for (int d = 0; d < 32; ++d) {
            float qv = qdl[i][d];
            #pragma unroll
            for (int j = 0; j < 16; ++j) s[j] += qv * kdl[j0 + j][d];
        }
        #pragma unroll
        for (int j = 0; j < 16; ++j) wsc[i][j0 + j] = s[j];
    }
    __syncthreads();
    if (t < 64) {
        float bv[4] = {-1e30f, -1e30f, -1e30f, -1e30f};
        int   bi[4] = {0, 0, 0, 0};
        for (int j = 0; j < 64; ++j) {
            float v = wsc[t][j];
            if (v > bv[3]) {
                int p = 3;
                while (p > 0 && v > bv[p - 1]) {
                    bv[p] = bv[p - 1]; bi[p] = bi[p - 1]; --p;
                }
                bv[p] = v; bi[p] = j;
            }
        }
        int* o = idx_out + (bh * 64 + t) * 4;
        o[0] = bi[0]; o[1] = bi[1]; o[2] = bi[2]; o[3] = bi[3];
    }
}

// ---------------------------------------------------------------- gathered window attention, MFMA
// One wave per window; 4 windows/block. Q loaded straight to registers;
// K/V staged bf16 in padded LDS (V transposed). QK^T/PV = 4 MFMA each.
__global__ __launch_bounds__(256) void attn_k(const unsigned short* __restrict__ qkv,
                                              const int* __restrict__ idx,
                                              unsigned short* __restrict__ msg) {
    __shared__ __align__(16) unsigned short ks[4][64][40];   // [key][d], +8 pad
    __shared__ __align__(16) unsigned short vt[4][32][72];   // [d][key], +8 pad
    __shared__ __align__(16) unsigned short ps[4][16][72];   // [tok][key], +8 pad
    const int t = threadIdx.x;
    const int wid = t >> 6, lane = t & 63;
    const int g = blockIdx.x * 4 + wid;        // global window id
    const int win = g & 63;
    const int bh = g >> 6;
    const int b = bh >> 3, h = bh & 7;
    const int qb = (win >> 3) * 128 + (win & 7) * 4;
    const int* widx = idx + (bh * 64 + win) * 4;

    // gather K (row-major) + V (transposed)
    for (int e = lane; e < 512; e += 64) {
        int key = e >> 3, d4 = (e & 7) * 4;
        int wsel = widx[key >> 4];
        int tok = key & 15;
        int hw = (wsel >> 3) * 128 + (wsel & 7) * 4 + (tok >> 2) * 32 + (tok & 3);
        size_t base = ((size_t)(b * 1024 + hw)) * 768 + h * 32 + d4;
        uint2 uk = *(const uint2*)&qkv[base + 256];
        uint2 uv = *(const uint2*)&qkv[base + 512];
        *(uint2*)&ks[wid][key][d4] = uk;
        vt[wid][d4 + 0][key] = (unsigned short)(uv.x & 0xffffu);
        vt[wid][d4 + 1][key] = (unsigned short)(uv.x >> 16);
        vt[wid][d4 + 2][key] = (unsigned short)(uv.y & 0xffffu);
        vt[wid][d4 + 3][key] = (unsigned short)(uv.y >> 16);
    }

    const int lr = lane & 15;
    const int lk8 = (lane >> 4) * 8;
    const float scale = 0.17677669529663688f;   // 1/sqrt(32)
    f32x4 zero = {0.f, 0.f, 0.f, 0.f};

    // Q A-fragment direct from global: tok = lr, d = lk8..lk8+7 (16B aligned)
    int qhw = qb + (lr >> 2) * 32 + (lr & 3);
    bf16x8 qA = *(const bf16x8*)&qkv[((size_t)(b * 1024 + qhw)) * 768 + h * 32 + lk8];
    __syncthreads();

    // QK^T: S[16 q][64 key] = Q(A) x K^T(B), 4 n-tiles
    f32x4 sa[4];
    #pragma unroll
    for (int kt = 0; kt < 4; ++kt) {
        bf16x8 kB = *(const bf16x8*)&ks[wid][kt * 16 + lr][lk8];
        sa[kt] = __builtin_amdgcn_mfma_f32_16x16x32_bf16(qA, kB, zero, 0, 0, 0);
    }
    // softmax per q-row (row = (lane>>4)*4+i; key cols split lane&15 x kt)
    #pragma unroll
    for (int i = 0; i < 4; ++i) {
        float s0 = sa[0][i] * scale, s1 = sa[1][i] * scale;
        float s2 = sa[2][i] * scale, s3 = sa[3][i] * scale;
        float mx = fmaxf(fmaxf(s0, s1), fmaxf(s2, s3));
        #pragma unroll
        for (int m = 1; m < 16; m <<= 1) mx = fmaxf(mx, __shfl_xor(mx, m));
        float e0 = expf(s0 - mx), e1 = expf(s1 - mx);
        float e2 = expf(s2 - mx), e3 = expf(s3 - mx);
        float sm = e0 + e1 + e2 + e3;
        #pragma unroll
        for (int m = 1; m < 16; m <<= 1) sm += __shfl_xor(sm, m);
        float inv = 1.0f / sm;
        int row = (lane >> 4) * 4 + i;
        ps[wid][row][ 0 + lr] = f2b(e0 * inv);
        ps[wid][row][16 + lr] = f2b(e1 * inv);
        ps[wid][row][32 + lr] = f2b(e2 * inv);
        ps[wid][row][48 + lr] = f2b(e3 * inv);
    }
    __syncthreads();
    // PV: O[16 q][32 d] = P(A, K=64) x V(B via vt), 2 n-tiles x 2 k-halves
    f32x4 oa[2] = {zero, zero};
    #pragma unroll
    for (int kh = 0; kh < 2; ++kh) {
        bf16x8 pA = *(const bf16x8*)&ps[wid][lr][kh * 32 + lk8];
        #pragma unroll
        for (int nt = 0; nt < 2; ++nt) {
            bf16x8 vB = *(const bf16x8*)&vt[wid][nt * 16 + lr][kh * 32 + lk8];
            oa[nt] = __builtin_amdgcn_mfma_f32_16x16x32_bf16(pA, vB, oa[nt], 0, 0, 0);
        }
    }
    // store O (C-layout: col d = nt*16+lr, row tok = (lane>>4)*4+i)
    #pragma unroll
    for (int nt = 0; nt < 2; ++nt) {
        int d = nt * 16 + lr;
        #pragma unroll
        for (int i = 0; i < 4; ++i) {
            int tok = (lane >> 4) * 4 + i;
            int hw = qb + (tok >> 2) * 32 + (tok & 3);
            msg[((size_t)(b * 1024 + hw)) * 256 + h * 32 + d] = f2b(oa[nt][i]);
        }
    }
}

// ---------------------------------------------------------------- K5: depthwise 3x3 + bn2 + gelu, vectorized
__global__ __launch_bounds__(256) void dw_k(const unsigned short* __restrict__ h1,
    const float* __restrict__ wt, const float* __restrict__ scf,
    const float* __restrict__ shf, unsigned short* __restrict__ h2) {
    int t = threadIdx.x;
    int c8 = t & 127;             // channel octet 0..127
    int pl = t >> 7;              // 0/1
    int blk = blockIdx.x;         // 2048 total: b(16) * y(32) * xg(4)
    int b = blk >> 7;
    int rem = blk & 127;
    int y = rem >> 2;
    int x0 = (rem & 3) * 8;
    int ch0 = c8 * 8;

    float w[9][8];
    #pragma unroll
    for (int tap = 0; tap < 9; ++tap) {
        float4 a = *(const float4*)(wt + tap * 1024 + ch0);
        float4 bq = *(const float4*)(wt + tap * 1024 + ch0 + 4);
        w[tap][0] = a.x; w[tap][1] = a.y; w[tap][2] = a.z; w[tap][3] = a.w;
        w[tap][4] = bq.x; w[tap][5] = bq.y; w[tap][6] = bq.z; w[tap][7] = bq.w;
    }
    float sc[8], sh[8];
    {
        float4 a = *(const float4*)(scf + ch0);
        float4 bq = *(const float4*)(scf + ch0 + 4);
        sc[0]=a.x; sc[1]=a.y; sc[2]=a.z; sc[3]=a.w; sc[4]=bq.x; sc[5]=bq.y; sc[6]=bq.z; sc[7]=bq.w;
        float4 c = *(const float4*)(shf + ch0);
        float4 dq = *(const float4*)(shf + ch0 + 4);
        sh[0]=c.x; sh[1]=c.y; sh[2]=c.z; sh[3]=c.w; sh[4]=dq.x; sh[5]=dq.y; sh[6]=dq.z; sh[7]=dq.w;
    }

    const unsigned short* base = h1 + (size_t)b * 1048576;
    unsigned short* ob = h2 + (size_t)b * 1048576;

    #pragma unroll
    for (int j = 0; j < 4; ++j) {
        int x = x0 + pl + 2 * j;
        float acc[8] = {0.f,0.f,0.f,0.f,0.f,0.f,0.f,0.f};
        #pragma unroll
        for (int dy = -1; dy <= 1; ++dy) {
            int yy = y + dy;
            if (yy < 0 || yy > 31) continue;
            #pragma unroll
            for (int dx = -1; dx <= 1; ++dx) {
                int xx = x + dx;
                if (xx < 0 || xx > 31) continue;
                uint4 u = *(const uint4*)(base + (size_t)(yy * 32 + xx) * 1024 + ch0);
                int tap = (dy + 1) * 3 + (dx + 1);
                acc[0] += lo16f(u.x) * w[tap][0];
                acc[1] += hi16f(u.x) * w[tap][1];
                acc[2] += lo16f(u.y) * w[tap][2];
                acc[3] += hi16f(u.y) * w[tap][3];
                acc[4] += lo16f(u.z) * w[tap][4];
                acc[5] += hi16f(u.z) * w[tap][5];
                acc[6] += lo16f(u.w) * w[tap][6];
                acc[7] += hi16f(u.w) * w[tap][7];
            }
        }
        unsigned short r[8];
        #pragma unroll
        for (int c = 0; c < 8; ++c)
            r[c] = f2b(gelu_f(acc[c] * sc[c] + sh[c]));
        uint4 o;
        o.x = (unsigned)r[0] | ((unsigned)r[1] << 16);
        o.y = (unsigned)r[2] | ((unsigned)r[3] << 16);
        o.z = (unsigned)r[4] | ((unsigned)r[5] << 16);
        o.w = (unsigned)r[6] | ((unsigned)r[7] << 16);
        *(uint4*)(ob + (size_t)(y * 32 + x) * 1024 + ch0) = o;
    }
}

// ---------------------------------------------------------------- launch
extern "C" void kernel_launch(void* const* d_in, const int* in_sizes, int n_in,
                              void* d_out, int out_size, void* d_ws, size_t ws_size,
                              hipStream_t stream) {
    const float* x      = (const float*)d_in[0];
    const float* bn0_g  = (const float*)d_in[1];
    const float* bn0_b  = (const float*)d_in[2];
    const float* bn0_m  = (const float*)d_in[3];
    const float* bn0_v  = (const float*)d_in[4];
    const float* w_qkv  = (const float*)d_in[5];
    const float* w_merge= (const float*)d_in[6];
    const float* b_merge= (const float*)d_in[7];
    const float* w1     = (const float*)d_in[8];
    const float* bn1_g  = (const float*)d_in[9];
    const float* bn1_b  = (const float*)d_in[10];
    const float* bn1_m  = (const float*)d_in[11];
    const float* bn1_v  = (const float*)d_in[12];
    const float* dw     = (const float*)d_in[13];
    const float* bn2_g  = (const float*)d_in[14];
    const float* bn2_b  = (const float*)d_in[15];
    const float* bn2_m  = (const float*)d_in[16];
    const float* bn2_v  = (const float*)d_in[17];
    const float* w2     = (const float*)d_in[18];
    const float* bn3_g  = (const float*)d_in[19];
    const float* bn3_b  = (const float*)d_in[20];
    const float* bn3_m  = (const float*)d_in[21];
    const float* bn3_v  = (const float*)d_in[22];
    float* out = (float*)d_out;

    char* w = (char*)d_ws;
    unsigned short* h0b   = (unsigned short*)(w);                // [b][hw][256] bf16
    unsigned short* qkvb  = (unsigned short*)(w + 8388608);      // [b][hw][768] bf16
    unsigned short* msgb  = (unsigned short*)(w + 33554432);     // [b][hw][256] bf16
    unsigned short* xrb   = (unsigned short*)(w + 41943040);     // [b][hw][256] bf16
    unsigned short* h1b   = (unsigned short*)(w + 50331648);     // [b][hw][1024] bf16
    unsigned short* h2b   = (unsigned short*)(w + 83886080);     // [b][hw][1024] bf16
    float*  xt    = (float*)(w + 117440512);                     // [b][hw][256] f32 (raw x)
    float*  xrf   = (float*)(w + 134217728);                     // [b][hw][256] f32
    float*  hm    = (float*)(w + 167772160);                     // [b][64][256] f32
    unsigned short* wqkvb = (unsigned short*)(w + 168820736);
    unsigned short* wmrgb = (unsigned short*)(w + 169213952);
    unsigned short* w1b   = (unsigned short*)(w + 169345024);
    unsigned short* w2b   = (unsigned short*)(w + 169869312);
    int*    idx   = (int*)(w + 170393600);                       // 131072 B
    float*  wtbuf = (float*)(w + 170524672);                     // 9*1024 f32
    float*  scbuf = (float*)(w + 170561536);                     // 1024 f32
    float*  shbuf = (float*)(w + 170565632);                     // 1024 f32
    float*  qkdbuf= (float*)(w + 170569728);                     // [1024][512] f32 (2 MB)

    // all weights -> bf16 (single launch) + dw prep
    wcvt4_k<<<768, 256, 0, stream>>>(w_qkv, w_merge, w1, w2, wqkvb, wmrgb, w1b, w2b);
    wprep_k<<<4, 256, 0, stream>>>(dw, bn2_g, bn2_b, bn2_m, bn2_v, wtbuf, scbuf, shbuf);

    // bn0+gelu + transpose to NHWC
    bn0tr_k<<<dim3(16, 4, 16), 256, 0, stream>>>(x, bn0_g, bn0_b, bn0_m, bn0_v, h0b, xt);
    // exact f32 window means
    hm_k<<<1024, 256, 0, stream>>>(xt, bn0_g, bn0_b, bn0_m, bn0_v, hm);
    // qkv = w_qkv @ h0
    mgemm<0><<<dim3(8, 6, 16), 256, 0, stream>>>(wqkvb, h0b, qkvb, nullptr,
        nullptr, nullptr, nullptr, nullptr, nullptr, 768, 256);
    // descriptors (tiled f32 GEMM) + top-k
    desc2_k<<<dim3(16, 8), 256, 0, stream>>>(hm, w_qkv, qkdbuf);
    aff_k<<<128, 256, 0, stream>>>(qkdbuf, idx);
    // attention (MFMA, 4 windows/block)
    attn_k<<<2048, 256, 0, stream>>>(qkvb, idx, msgb);
    // xr = x + w_merge@msg + bias
    mgemm<1><<<dim3(8, 2, 16), 256, 0, stream>>>(wmrgb, msgb, xrb, xrf,
        xt, b_merge, nullptr, nullptr, nullptr, 256, 256);
    // h1 = gelu(bn1(w1@xr))
    mgemm<2><<<dim3(8, 8, 16), 256, 0, stream>>>(w1b, xrb, h1b, nullptr,
        nullptr, bn1_g, bn1_b, bn1_m, bn1_v, 1024, 256);
    // h2 = gelu(bn2(dw3x3(h1)))  — vectorized
    dw_k<<<2048, 256, 0, stream>>>(h1b, wtbuf, scbuf, shbuf, h2b);
    // out = bn3(w2@h2) + xr  — stored directly NCHW (trout fused)
    mgemm<3><<<dim3(8, 2, 16), 256, 0, stream>>>(w2b, h2b, nullptr, out,
        xrf, bn3_g, bn3_b, bn3_m, bn3_v, 256, 1024);
}